// Round 1
// baseline (3047.832 us; speedup 1.0000x reference)
//
#include <hip/hip_runtime.h>
#include <math.h>

#define TPB 256

constexpr int Bn = 64, Kc = 24, TSz = 11;
constexpr int NBK = Bn * Kc;          // 1536
constexpr int CH = 384;               // (b,k) instances per chunk
constexpr int NCHUNK = NBK / CH;      // 4
constexpr int P1 = 19 * 19, P2 = 81, P3 = 49, P4 = 25;

// ---- workspace offsets (floats) ----
constexpr size_t SZ_WT   = (size_t)Kc * 128 * 9 * 128;       // 3538944
constexpr size_t OFF_WT2 = 0;
constexpr size_t OFF_WT3 = OFF_WT2 + SZ_WT;
constexpr size_t OFF_WT4 = OFF_WT3 + SZ_WT;
constexpr size_t OFF_H1  = OFF_WT4 + SZ_WT;
constexpr size_t OFF_H2  = OFF_H1 + (size_t)CH * P1 * 128;
constexpr size_t OFF_H3  = OFF_H2 + (size_t)CH * P2 * 128;
constexpr size_t OFF_H4  = OFF_H3 + (size_t)CH * P3 * 128;
constexpr size_t OFF_POSE= OFF_H4 + (size_t)CH * P4 * 128;
constexpr size_t OFF_DMV = OFF_POSE + (size_t)NBK * 6;
constexpr size_t OFF_TT  = OFF_DMV + NBK;
constexpr size_t OFF_ST  = OFF_TT + (size_t)NBK * 1600;
constexpr size_t OFF_MXS = OFF_ST + 128;
constexpr size_t OFF_PART= OFF_MXS + (size_t)NBK * 2;

// ---- output offsets (floats) ----
constexpr int OUT_OC = 1;                   // input_ocae [B,K,136]
constexpr int OUT_XM = 1 + NBK * 136;       // 208897
constexpr int OUT_DM = OUT_XM + NBK * 6;    // 218113

// ============ reductions ============
__device__ __forceinline__ float blockReduceSum(float v) {
    __shared__ float red[4];
    __syncthreads();
#pragma unroll
    for (int o = 32; o > 0; o >>= 1) v += __shfl_down(v, o, 64);
    int lane = threadIdx.x & 63, wv = threadIdx.x >> 6;
    if (lane == 0) red[wv] = v;
    __syncthreads();
    return red[0] + red[1] + red[2] + red[3];
}

__device__ __forceinline__ float blockReduceMax(float v) {
    __shared__ float redm[4];
    __syncthreads();
#pragma unroll
    for (int o = 32; o > 0; o >>= 1) v = fmaxf(v, __shfl_down(v, o, 64));
    int lane = threadIdx.x & 63, wv = threadIdx.x >> 6;
    if (lane == 0) redm[wv] = v;
    __syncthreads();
    return fmaxf(fmaxf(redm[0], redm[1]), fmaxf(redm[2], redm[3]));
}

// ============ weight transpose: [k][c2][c][tap] -> [k][c][tap][c2] ============
__global__ __launch_bounds__(TPB) void tw_k(const float* __restrict__ w,
                                            float* __restrict__ wt) {
    __shared__ float t[64][65];
    const int k = blockIdx.x >> 1, half = blockIdx.x & 1;
    const float* src = w + (size_t)(k * 128 + half * 64) * 1152;
    float* dst = wt + (size_t)k * 128 * 9 * 128 + half * 64;
    for (int cc = 0; cc < 18; ++cc) {
        __syncthreads();
        for (int i = threadIdx.x; i < 64 * 64; i += TPB) {
            int r = i >> 6, col = i & 63;
            t[r][col] = src[(size_t)r * 1152 + cc * 64 + col];
        }
        __syncthreads();
        for (int i = threadIdx.x; i < 64 * 64; i += TPB) {
            int c2l = i & 63, ctl = i >> 6;
            int ct = cc * 64 + ctl;
            int cch = ct / 9, tap = ct - cch * 9;
            dst[(size_t)(cch * 9 + tap) * 128 + c2l] = t[c2l][ctl];
        }
    }
}

// ============ conv1: x[B,1,40,40] -> h1[CH][361][128], stride 2, relu ============
__global__ __launch_bounds__(TPB) void conv1_k(const float* __restrict__ x,
                                               const float* __restrict__ w1,
                                               const float* __restrict__ b1,
                                               float* __restrict__ h1, int bk0) {
    int idx = blockIdx.x * TPB + threadIdx.x;   // exact: CH*361*128
    int c = idx & 127;
    int t = idx >> 7;
    int bkL = t / 361;
    int pos = t - bkL * 361;
    int bk = bk0 + bkL;
    int b = bk / Kc, k = bk - b * Kc;
    int y = pos / 19, xx = pos - y * 19;
    const float* xb = x + b * 1600 + (y * 2) * 40 + xx * 2;
    const float* wp = w1 + (size_t)(k * 128 + c) * 9;
    float s = b1[k * 128 + c];
#pragma unroll
    for (int dy = 0; dy < 3; ++dy)
#pragma unroll
        for (int dx = 0; dx < 3; ++dx)
            s += wp[dy * 3 + dx] * xb[dy * 40 + dx];
    h1[idx] = fmaxf(s, 0.f);
}

// ============ generic 3x3 conv, 128->128, relu, channels-last ============
template <int IH, int IW, int OH, int OW, int ST, int NPJ>
__global__ __launch_bounds__(TPB) void convN_k(const float* __restrict__ hin,
                                               const float* __restrict__ wt,
                                               const float* __restrict__ bias,
                                               float* __restrict__ hout, int bk0) {
    constexpr int IP = IH * IW, OP = OH * OW;
    __shared__ float hs[IP * 16];
    const int bkL = blockIdx.x >> 1, half = blockIdx.x & 1;
    const int k = (bk0 + bkL) % Kc;
    const int lane = threadIdx.x & 63;
    const int par = threadIdx.x >> 6;   // 0..3, uniform per wave
    const int c2 = half * 64 + lane;
    float acc[NPJ];
#pragma unroll
    for (int j = 0; j < NPJ; ++j) acc[j] = 0.f;
    const float* hb = hin + (size_t)bkL * IP * 128;
    const float* wb = wt + (size_t)k * 128 * 9 * 128 + c2;
    for (int cb = 0; cb < 8; ++cb) {
        __syncthreads();
        for (int i = threadIdx.x; i < IP * 16; i += TPB)
            hs[i] = hb[(size_t)(i >> 4) * 128 + cb * 16 + (i & 15)];
        __syncthreads();
        for (int c = 0; c < 16; ++c) {
            const float* wp = wb + (size_t)((cb * 16 + c) * 9) * 128;
            float w[9];
#pragma unroll
            for (int t = 0; t < 9; ++t) w[t] = wp[(size_t)t * 128];
            const float* hc = hs + c;
#pragma unroll
            for (int j = 0; j < NPJ; ++j) {
                int pix = par + 4 * j;
                if (pix < OP) {
                    int oy = pix / OW, ox = pix - oy * OW;
                    const float* hp = hc + ((oy * ST) * IW + ox * ST) * 16;
                    float s = 0.f;
#pragma unroll
                    for (int dy = 0; dy < 3; ++dy)
#pragma unroll
                        for (int dx = 0; dx < 3; ++dx)
                            s += w[dy * 3 + dx] * hp[(dy * IW + dx) * 16];
                    acc[j] += s;
                }
            }
        }
    }
    const float bv = bias[k * 128 + c2];
    float* ho = hout + (size_t)bkL * OP * 128 + c2;
#pragma unroll
    for (int j = 0; j < NPJ; ++j) {
        int pix = par + 4 * j;
        if (pix < OP) ho[(size_t)pix * 128] = fmaxf(acc[j] + bv, 0.f);
    }
}

// ============ conv5 (1x1) + attention + pooling + heads + ocae assembly ============
__global__ __launch_bounds__(TPB) void head_k(const float* __restrict__ h4,
                                              const float* __restrict__ w5,
                                              const float* __restrict__ b5,
                                              const float* __restrict__ tpl,
                                              float* __restrict__ pose,
                                              float* __restrict__ dmv,
                                              float* __restrict__ out, int bk0) {
    __shared__ float h4s[128 * 25];   // [c][pix]
    __shared__ float outs[16 * 25];   // [f][pix]
    __shared__ float atts[25];
    __shared__ float pooled[16];
    const int bk = bk0 + blockIdx.x;
    const int k = bk % Kc;
    const float* hb = h4 + (size_t)blockIdx.x * 25 * 128;
    for (int i = threadIdx.x; i < 25 * 128; i += TPB) {
        int pix = i >> 7, c = i & 127;
        h4s[c * 25 + pix] = hb[i];
    }
    __syncthreads();
    for (int t = threadIdx.x; t < 400; t += TPB) {
        int f = t / 25, pix = t - f * 25;
        const float* wp = w5 + (size_t)(k * 16 + f) * 128;
        float s = b5[k * 16 + f];
        for (int c = 0; c < 128; ++c) s += wp[c] * h4s[c * 25 + pix];
        outs[t] = s;
    }
    __syncthreads();
    if (threadIdx.x < 25) {
        int y5 = threadIdx.x / 5;
        const float* row = outs + 15 * 25 + y5 * 5;
        float mx = row[0];
#pragma unroll
        for (int j = 1; j < 5; ++j) mx = fmaxf(mx, row[j]);
        float ssum = 0.f;
#pragma unroll
        for (int j = 0; j < 5; ++j) ssum += expf(row[j] - mx);
        atts[threadIdx.x] = expf(outs[15 * 25 + threadIdx.x] - mx) / ssum;
    }
    __syncthreads();
    if (threadIdx.x < 15) {
        float s = 0.f;
        const float* row = outs + threadIdx.x * 25;
#pragma unroll
        for (int p = 0; p < 25; ++p) s += row[p] * atts[p];
        pooled[threadIdx.x] = s;
    }
    __syncthreads();
    float* oc = out + OUT_OC + (size_t)bk * 136;
    if (threadIdx.x < 6) {
        float v = fmaxf(pooled[threadIdx.x], 0.f);
        pose[bk * 6 + threadIdx.x] = v;
        oc[1 + threadIdx.x] = v;
        out[OUT_XM + bk * 6 + threadIdx.x] = v;
    } else if (threadIdx.x == 6) {
        float d = 1.f / (1.f + expf(-pooled[6]));
        dmv[bk] = d;
        oc[0] = d;
        out[OUT_DM + bk] = d;
    } else if (threadIdx.x >= 7 && threadIdx.x < 15) {
        oc[128 + threadIdx.x - 7] = fmaxf(pooled[threadIdx.x], 0.f);
    }
    for (int t = threadIdx.x; t < 121; t += TPB) oc[7 + t] = tpl[k * 121 + t];
}

// ============ affine warp + bilinear TS->40x40 ============
__device__ __forceinline__ float tapf(const float* tp, int y, int x) {
    bool valid = (x >= 0) && (x < TSz) && (y >= 0) && (y < TSz);
    int yc = min(max(y, 0), TSz - 1), xc = min(max(x, 0), TSz - 1);
    float v = tp[yc * TSz + xc];
    return valid ? v : 0.f;
}

__global__ __launch_bounds__(TPB) void warp_k(const float* __restrict__ pose,
                                              const float* __restrict__ tpl,
                                              float* __restrict__ tt) {
    __shared__ float tp[121];
    const int bk = blockIdx.x, k = bk % Kc;
    for (int i = threadIdx.x; i < 121; i += TPB) tp[i] = tpl[k * 121 + i];
    const float* ps = pose + bk * 6;
    const float D2R = 0.017453292519943295f;
    float ang = ps[0] * D2R, tx = ps[1], ty = ps[2];
    float sc = fmaxf(ps[3], 1e-2f);
    float shx = ps[4] * D2R, shy = ps[5] * D2R;
    float cams = cosf(ang - shy), sams = sinf(ang - shy);
    float cshy = cosf(shy), tshx = tanf(shx);
    float av = cams / cshy;
    float bv = -cams * tshx / cshy - sinf(ang);
    float cv = sams / cshy;
    float dv = -sams * tshx / cshy + cosf(ang);
    float m0 = dv / sc, m1 = -bv / sc, m3 = -cv / sc, m4 = av / sc;
    float m2 = m0 * (-5.f - tx) + m1 * (-5.f - ty) + 5.f;
    float m5 = m3 * (-5.f - tx) + m4 * (-5.f - ty) + 5.f;
    __syncthreads();
    float* to = tt + (size_t)bk * 1600;
    for (int p = threadIdx.x; p < 1600; p += TPB) {
        int i = p / 40, j = p - (p / 40) * 40;
        float gx = (j + 0.5f) * (11.f / 40.f) - 0.5f;
        float gy = (i + 0.5f) * (11.f / 40.f) - 0.5f;
        float xin = m0 * gx + m1 * gy + m2;
        float yin = m3 * gx + m4 * gy + m5;
        float x0 = floorf(xin), y0 = floorf(yin);
        float wx = xin - x0, wy = yin - y0;
        int x0i = (int)x0, y0i = (int)y0;
        float v00 = tapf(tp, y0i, x0i),     v01 = tapf(tp, y0i, x0i + 1);
        float v10 = tapf(tp, y0i + 1, x0i), v11 = tapf(tp, y0i + 1, x0i + 1);
        to[p] = v00 * (1.f - wx) * (1.f - wy) + v01 * wx * (1.f - wy) +
                v10 * (1.f - wx) * wy + v11 * wx * wy;
    }
}

// ============ per-sample std stats ============
__global__ __launch_bounds__(TPB) void std_k(const float* __restrict__ x,
                                             float* __restrict__ st) {
    const int b = blockIdx.x;
    const float* xb = x + b * 1600;
    float s = 0.f, s2 = 0.f;
    for (int p = threadIdx.x; p < 1600; p += TPB) {
        float v = xb[p];
        s += v; s2 += v * v;
    }
    s = blockReduceSum(s);
    s2 = blockReduceSum(s2);
    if (threadIdx.x == 0) {
        float mean = s / 1600.f;
        float var = (s2 - 1600.f * mean * mean) / 1599.f;
        float sd = sqrtf(var);
        st[b * 2] = rsqrtf(sd * 6.283185307179586f);   // mult
        st[b * 2 + 1] = -1.f / (2.f * sd * sd);        // pw
    }
}

// ============ mix softmax stats: max + sum over 1600 pixels ============
__global__ __launch_bounds__(TPB) void mix1_k(const float* __restrict__ tt,
                                              const float* __restrict__ dmv,
                                              float* __restrict__ mxs) {
    const int bk = blockIdx.x;
    const float dm = dmv[bk];
    const float* t = tt + (size_t)bk * 1600;
    float mx = -1e30f;
    for (int p = threadIdx.x; p < 1600; p += TPB) mx = fmaxf(mx, dm * t[p]);
    mx = blockReduceMax(mx);
    float s = 0.f;
    for (int p = threadIdx.x; p < 1600; p += TPB) s += expf(dm * t[p] - mx);
    s = blockReduceSum(s);
    if (threadIdx.x == 0) { mxs[bk * 2] = mx; mxs[bk * 2 + 1] = s; }
}

// ============ log-likelihood per sample ============
__global__ __launch_bounds__(TPB) void ll_k(const float* __restrict__ x,
                                            const float* __restrict__ tt,
                                            const float* __restrict__ dmv,
                                            const float* __restrict__ mxs,
                                            const float* __restrict__ st,
                                            float* __restrict__ part) {
    const int b = blockIdx.x;
    __shared__ float dms[24], mxh[24], sih[24];
    if (threadIdx.x < 24) {
        int bk = b * 24 + threadIdx.x;
        dms[threadIdx.x] = dmv[bk];
        mxh[threadIdx.x] = mxs[bk * 2];
        sih[threadIdx.x] = 1.f / mxs[bk * 2 + 1];
    }
    __syncthreads();
    const float mult = st[b * 2], pw = st[b * 2 + 1];
    const float* xb = x + b * 1600;
    const float* tb = tt + (size_t)b * 24 * 1600;
    float acc = 0.f;
    for (int p = threadIdx.x; p < 1600; p += TPB) {
        float xv = xb[p];
        float ssum = 0.f;
        for (int k = 0; k < 24; ++k) {
            float tv = tb[(size_t)k * 1600 + p];
            float dd = xv - tv;
            float g = mult * expf(dd * dd * pw);
            float mixv = expf(dms[k] * tv - mxh[k]) * sih[k];
            ssum += g * mixv;
        }
        acc += logf(ssum);
    }
    acc = blockReduceSum(acc);
    if (threadIdx.x == 0) part[b] = acc;
}

__global__ void fin_k(const float* __restrict__ part, float* __restrict__ out) {
    float v = part[threadIdx.x];   // 64 threads, one wave
#pragma unroll
    for (int o = 32; o > 0; o >>= 1) v += __shfl_down(v, o, 64);
    if (threadIdx.x == 0) out[0] = v * (1.f / 64.f);
}

// ============ launch ============
extern "C" void kernel_launch(void* const* d_in, const int* in_sizes, int n_in,
                              void* d_out, int out_size, void* d_ws, size_t ws_size,
                              hipStream_t stream) {
    const float* x   = (const float*)d_in[0];
    const float* w1  = (const float*)d_in[1];
    const float* b1  = (const float*)d_in[2];
    const float* w2  = (const float*)d_in[3];
    const float* b2  = (const float*)d_in[4];
    const float* w3  = (const float*)d_in[5];
    const float* b3  = (const float*)d_in[6];
    const float* w4  = (const float*)d_in[7];
    const float* b4  = (const float*)d_in[8];
    const float* w5  = (const float*)d_in[9];
    const float* b5  = (const float*)d_in[10];
    const float* tpl = (const float*)d_in[11];
    float* out = (float*)d_out;
    float* ws = (float*)d_ws;

    float* wt2 = ws + OFF_WT2;
    float* wt3 = ws + OFF_WT3;
    float* wt4 = ws + OFF_WT4;
    float* h1  = ws + OFF_H1;
    float* h2  = ws + OFF_H2;
    float* h3  = ws + OFF_H3;
    float* h4  = ws + OFF_H4;
    float* pose= ws + OFF_POSE;
    float* dmv = ws + OFF_DMV;
    float* ttb = ws + OFF_TT;
    float* stv = ws + OFF_ST;
    float* mxs = ws + OFF_MXS;
    float* part= ws + OFF_PART;

    tw_k<<<48, TPB, 0, stream>>>(w2, wt2);
    tw_k<<<48, TPB, 0, stream>>>(w3, wt3);
    tw_k<<<48, TPB, 0, stream>>>(w4, wt4);
    std_k<<<Bn, TPB, 0, stream>>>(x, stv);

    for (int ch = 0; ch < NCHUNK; ++ch) {
        int bk0 = ch * CH;
        conv1_k<<<CH * P1 * 128 / TPB, TPB, 0, stream>>>(x, w1, b1, h1, bk0);
        convN_k<19, 19, 9, 9, 2, 21><<<CH * 2, TPB, 0, stream>>>(h1, wt2, b2, h2, bk0);
        convN_k<9, 9, 7, 7, 1, 13><<<CH * 2, TPB, 0, stream>>>(h2, wt3, b3, h3, bk0);
        convN_k<7, 7, 5, 5, 1, 7><<<CH * 2, TPB, 0, stream>>>(h3, wt4, b4, h4, bk0);
        head_k<<<CH, TPB, 0, stream>>>(h4, w5, b5, tpl, pose, dmv, out, bk0);
    }

    warp_k<<<NBK, TPB, 0, stream>>>(pose, tpl, ttb);
    mix1_k<<<NBK, TPB, 0, stream>>>(ttb, dmv, mxs);
    ll_k<<<Bn, TPB, 0, stream>>>(x, ttb, dmv, mxs, stv, part);
    fin_k<<<1, 64, 0, stream>>>(part, out);
}

// Round 2
// 1447.441 us; speedup vs baseline: 2.1057x; 2.1057x over previous
//
#include <hip/hip_runtime.h>
#include <math.h>

#define TPB 256

typedef __attribute__((ext_vector_type(8))) short s16x8;
typedef __attribute__((ext_vector_type(4))) float f32x4;

constexpr int Bn = 64, Kc = 24, TSz = 11;
constexpr int NBK = Bn * Kc;          // 1536
constexpr int CH = 384;               // (b,k) instances per chunk
constexpr int NCHUNK = NBK / CH;      // 4
constexpr int P1 = 361, P2 = 81, P3 = 49, P4 = 25;

// ---- workspace offsets (BYTES) ----
constexpr size_t SZW_US   = (size_t)Kc * 4 * 9 * 128 * 32;   // 3538944 ushorts/plane
constexpr size_t OFFB_W2H = 0;
constexpr size_t OFFB_W2L = OFFB_W2H + SZW_US * 2;
constexpr size_t OFFB_W3H = OFFB_W2L + SZW_US * 2;
constexpr size_t OFFB_W3L = OFFB_W3H + SZW_US * 2;
constexpr size_t OFFB_W4H = OFFB_W3L + SZW_US * 2;
constexpr size_t OFFB_W4L = OFFB_W4H + SZW_US * 2;
constexpr size_t OFFB_H1  = OFFB_W4L + SZW_US * 2;
constexpr size_t OFFB_H2  = OFFB_H1 + (size_t)CH * P1 * 128 * 2;
constexpr size_t OFFB_H3  = OFFB_H2 + (size_t)CH * P2 * 128 * 2;
constexpr size_t OFFB_H4  = OFFB_H3 + (size_t)CH * P3 * 128 * 2;
constexpr size_t OFFB_POSE= OFFB_H4 + (size_t)CH * P4 * 128 * 4;
constexpr size_t OFFB_DMV = OFFB_POSE + (size_t)NBK * 6 * 4;
constexpr size_t OFFB_TT  = OFFB_DMV + (size_t)NBK * 4;
constexpr size_t OFFB_ST  = OFFB_TT + (size_t)NBK * 1600 * 4;
constexpr size_t OFFB_MXS = OFFB_ST + 512;
constexpr size_t OFFB_PART= OFFB_MXS + (size_t)NBK * 2 * 4;

// ---- output offsets (floats) ----
constexpr int OUT_OC = 1;                   // input_ocae [B,K,136]
constexpr int OUT_XM = 1 + NBK * 136;
constexpr int OUT_DM = OUT_XM + NBK * 6;

// ============ bf16 helpers ============
__device__ __forceinline__ ushort f2b(float f) {
    union { float f; unsigned u; } c; c.f = f;
    unsigned r = c.u + 0x7fffu + ((c.u >> 16) & 1u);
    return (ushort)(r >> 16);
}
__device__ __forceinline__ float b2f(ushort h) {
    union { unsigned u; float f; } c; c.u = ((unsigned)h) << 16; return c.f;
}

// ============ reductions ============
__device__ __forceinline__ float blockReduceSum(float v) {
    __shared__ float red[4];
    __syncthreads();
#pragma unroll
    for (int o = 32; o > 0; o >>= 1) v += __shfl_down(v, o, 64);
    int lane = threadIdx.x & 63, wv = threadIdx.x >> 6;
    if (lane == 0) red[wv] = v;
    __syncthreads();
    return red[0] + red[1] + red[2] + red[3];
}

__device__ __forceinline__ float blockReduceMax(float v) {
    __shared__ float redm[4];
    __syncthreads();
#pragma unroll
    for (int o = 32; o > 0; o >>= 1) v = fmaxf(v, __shfl_down(v, o, 64));
    int lane = threadIdx.x & 63, wv = threadIdx.x >> 6;
    if (lane == 0) redm[wv] = v;
    __syncthreads();
    return fmaxf(fmaxf(redm[0], redm[1]), fmaxf(redm[2], redm[3]));
}

// ============ weight prep: w[k][cout][cin][tap] f32 -> hi/lo bf16 [k][cb][tap][cout][32] ============
__global__ __launch_bounds__(128) void wprep_k(const float* __restrict__ w,
                                               ushort* __restrict__ wth,
                                               ushort* __restrict__ wtl) {
    __shared__ float ld[1152];
    const int k = blockIdx.x >> 7, cout = blockIdx.x & 127;
    const float* src = w + (size_t)(k * 128 + cout) * 1152;
    for (int i = threadIdx.x; i < 1152; i += 128) ld[i] = src[i];
    __syncthreads();
    for (int e = threadIdx.x; e < 1152; e += 128) {
        int cb = e / 288, r = e - cb * 288, tap = r / 32, c32 = r - tap * 32;
        int cin = cb * 32 + c32;
        float v = ld[cin * 9 + tap];
        ushort hi = f2b(v);
        float lo = v - b2f(hi);
        size_t d = (((size_t)(k * 4 + cb) * 9 + tap) * 128 + cout) * 32 + c32;
        wth[d] = hi; wtl[d] = f2b(lo);
    }
}

// ============ conv1: x[B,1,40,40] -> h1[CH][361][128] bf16, stride 2, relu ============
__global__ __launch_bounds__(TPB) void conv1_k(const float* __restrict__ x,
                                               const float* __restrict__ w1,
                                               const float* __restrict__ b1,
                                               ushort* __restrict__ h1, int bk0) {
    int idx = blockIdx.x * TPB + threadIdx.x;   // exact: CH*361*128
    int c = idx & 127;
    int t = idx >> 7;
    int bkL = t / 361;
    int pos = t - bkL * 361;
    int bk = bk0 + bkL;
    int b = bk / Kc, k = bk - b * Kc;
    int y = pos / 19, xx = pos - y * 19;
    const float* xb = x + b * 1600 + (y * 2) * 40 + xx * 2;
    const float* wp = w1 + (size_t)(k * 128 + c) * 9;
    float s = b1[k * 128 + c];
#pragma unroll
    for (int dy = 0; dy < 3; ++dy)
#pragma unroll
        for (int dx = 0; dx < 3; ++dx)
            s += wp[dy * 3 + dx] * xb[dy * 40 + dx];
    h1[idx] = f2b(fmaxf(s, 0.f));
}

// ============ MFMA implicit-GEMM conv: bf16 act x (hi/lo bf16) weights ============
// A (im2col) staged in LDS per 32-cin slab; B direct from global (L1/L2).
// K-order (cb, tap, cin8) identical for A and B -> hw k-permutation cancels.
template <int IH, int IW, int OH, int OW, int ST, int NW, int MW, bool F32OUT>
__global__ __launch_bounds__(NW * 64) void mfconv_k(
    const ushort* __restrict__ hin, const ushort* __restrict__ wth,
    const ushort* __restrict__ wtl, const float* __restrict__ bias,
    ushort* __restrict__ hout, float* __restrict__ houtf, int bk0) {
    constexpr int IP = IH * IW, OP = OH * OW;
    __shared__ ushort As[IP * 40];     // row stride 40 bf16 (80B): quad=5*ipix mod 8
    const int bkL = blockIdx.x;
    const int k = (bk0 + bkL) % Kc;
    const int tid = threadIdx.x;
    const int wv = tid >> 6, l = tid & 63, l16 = l & 15, g = l >> 4;
    constexpr int NT = NW * 64;

    f32x4 acc[MW][8];
#pragma unroll
    for (int m = 0; m < MW; ++m)
#pragma unroll
        for (int n = 0; n < 8; ++n) acc[m][n] = (f32x4)0.f;

    int ibase[MW];
#pragma unroll
    for (int m = 0; m < MW; ++m) {
        int opix = (wv * MW + m) * 16 + l16;
        opix = opix < OP ? opix : OP - 1;     // clamp pad rows to valid memory
        int oy = opix / OW, ox = opix - oy * OW;
        ibase[m] = oy * ST * IW + ox * ST;
    }
    const ushort* hsrc = hin + (size_t)bkL * IP * 128;

    for (int cb = 0; cb < 4; ++cb) {
        __syncthreads();
        for (int i = tid; i < IP * 4; i += NT) {
            int row = i >> 2, gc = i & 3;
            s16x8 v = *(const s16x8*)(hsrc + row * 128 + cb * 32 + gc * 8);
            *(s16x8*)(As + row * 40 + 8 * (gc ^ ((row >> 3) & 1))) = v;
        }
        __syncthreads();
        const ushort* wbh = wth + ((size_t)(k * 4 + cb) * 9) * 4096 + l16 * 32 + g * 8;
        const ushort* wbl = wtl + ((size_t)(k * 4 + cb) * 9) * 4096 + l16 * 32 + g * 8;
        for (int tap = 0; tap < 9; ++tap) {
            const int ioff = (tap / 3) * IW + (tap % 3);
            s16x8 a[MW];
#pragma unroll
            for (int m = 0; m < MW; ++m) {
                int ip = ibase[m] + ioff;
                a[m] = *(const s16x8*)(As + ip * 40 + 8 * (g ^ ((ip >> 3) & 1)));
            }
            const ushort* ph = wbh + tap * 4096;
            const ushort* pl = wbl + tap * 4096;
#pragma unroll
            for (int n = 0; n < 8; ++n) {
                s16x8 bh = *(const s16x8*)(ph + n * 512);
                s16x8 bl = *(const s16x8*)(pl + n * 512);
#pragma unroll
                for (int m = 0; m < MW; ++m) {
                    acc[m][n] = __builtin_amdgcn_mfma_f32_16x16x32_bf16(a[m], bh, acc[m][n], 0, 0, 0);
                    acc[m][n] = __builtin_amdgcn_mfma_f32_16x16x32_bf16(a[m], bl, acc[m][n], 0, 0, 0);
                }
            }
        }
    }
    // epilogue: C/D map col=lane&15, row=(lane>>4)*4+r (m89-verified)
#pragma unroll
    for (int n = 0; n < 8; ++n) {
        int cout = n * 16 + l16;
        float bv = bias[k * 128 + cout];
#pragma unroll
        for (int m = 0; m < MW; ++m) {
#pragma unroll
            for (int r = 0; r < 4; ++r) {
                int opix = (wv * MW + m) * 16 + g * 4 + r;
                if (opix < OP) {
                    float v = fmaxf(acc[m][n][r] + bv, 0.f);
                    size_t o = ((size_t)bkL * OP + opix) * 128 + cout;
                    if (F32OUT) houtf[o] = v; else hout[o] = f2b(v);
                }
            }
        }
    }
}

// ============ conv5 (1x1) + attention + pooling + heads + ocae assembly ============
__global__ __launch_bounds__(TPB) void head_k(const float* __restrict__ h4,
                                              const float* __restrict__ w5,
                                              const float* __restrict__ b5,
                                              const float* __restrict__ tpl,
                                              float* __restrict__ pose,
                                              float* __restrict__ dmv,
                                              float* __restrict__ out, int bk0) {
    __shared__ float h4s[128 * 25];   // [c][pix]
    __shared__ float outs[16 * 25];   // [f][pix]
    __shared__ float atts[25];
    __shared__ float pooled[16];
    const int bk = bk0 + blockIdx.x;
    const int k = bk % Kc;
    const float* hb = h4 + (size_t)blockIdx.x * 25 * 128;
    for (int i = threadIdx.x; i < 25 * 128; i += TPB) {
        int pix = i >> 7, c = i & 127;
        h4s[c * 25 + pix] = hb[i];
    }
    __syncthreads();
    for (int t = threadIdx.x; t < 400; t += TPB) {
        int f = t / 25, pix = t - f * 25;
        const float* wp = w5 + (size_t)(k * 16 + f) * 128;
        float s = b5[k * 16 + f];
        for (int c = 0; c < 128; ++c) s += wp[c] * h4s[c * 25 + pix];
        outs[t] = s;
    }
    __syncthreads();
    if (threadIdx.x < 25) {
        int y5 = threadIdx.x / 5;
        const float* row = outs + 15 * 25 + y5 * 5;
        float mx = row[0];
#pragma unroll
        for (int j = 1; j < 5; ++j) mx = fmaxf(mx, row[j]);
        float ssum = 0.f;
#pragma unroll
        for (int j = 0; j < 5; ++j) ssum += expf(row[j] - mx);
        atts[threadIdx.x] = expf(outs[15 * 25 + threadIdx.x] - mx) / ssum;
    }
    __syncthreads();
    if (threadIdx.x < 15) {
        float s = 0.f;
        const float* row = outs + threadIdx.x * 25;
#pragma unroll
        for (int p = 0; p < 25; ++p) s += row[p] * atts[p];
        pooled[threadIdx.x] = s;
    }
    __syncthreads();
    float* oc = out + OUT_OC + (size_t)bk * 136;
    if (threadIdx.x < 6) {
        float v = fmaxf(pooled[threadIdx.x], 0.f);
        pose[bk * 6 + threadIdx.x] = v;
        oc[1 + threadIdx.x] = v;
        out[OUT_XM + bk * 6 + threadIdx.x] = v;
    } else if (threadIdx.x == 6) {
        float d = 1.f / (1.f + expf(-pooled[6]));
        dmv[bk] = d;
        oc[0] = d;
        out[OUT_DM + bk] = d;
    } else if (threadIdx.x >= 7 && threadIdx.x < 15) {
        oc[128 + threadIdx.x - 7] = fmaxf(pooled[threadIdx.x], 0.f);
    }
    for (int t = threadIdx.x; t < 121; t += TPB) oc[7 + t] = tpl[k * 121 + t];
}

// ============ affine warp + bilinear TS->40x40 ============
__device__ __forceinline__ float tapf(const float* tp, int y, int x) {
    bool valid = (x >= 0) && (x < TSz) && (y >= 0) && (y < TSz);
    int yc = min(max(y, 0), TSz - 1), xc = min(max(x, 0), TSz - 1);
    float v = tp[yc * TSz + xc];
    return valid ? v : 0.f;
}

__global__ __launch_bounds__(TPB) void warp_k(const float* __restrict__ pose,
                                              const float* __restrict__ tpl,
                                              float* __restrict__ tt) {
    __shared__ float tp[121];
    const int bk = blockIdx.x, k = bk % Kc;
    for (int i = threadIdx.x; i < 121; i += TPB) tp[i] = tpl[k * 121 + i];
    const float* ps = pose + bk * 6;
    const float D2R = 0.017453292519943295f;
    float ang = ps[0] * D2R, tx = ps[1], ty = ps[2];
    float sc = fmaxf(ps[3], 1e-2f);
    float shx = ps[4] * D2R, shy = ps[5] * D2R;
    float cams = cosf(ang - shy), sams = sinf(ang - shy);
    float cshy = cosf(shy), tshx = tanf(shx);
    float av = cams / cshy;
    float bv = -cams * tshx / cshy - sinf(ang);
    float cv = sams / cshy;
    float dv = -sams * tshx / cshy + cosf(ang);
    float m0 = dv / sc, m1 = -bv / sc, m3 = -cv / sc, m4 = av / sc;
    float m2 = m0 * (-5.f - tx) + m1 * (-5.f - ty) + 5.f;
    float m5 = m3 * (-5.f - tx) + m4 * (-5.f - ty) + 5.f;
    __syncthreads();
    float* to = tt + (size_t)bk * 1600;
    for (int p = threadIdx.x; p < 1600; p += TPB) {
        int i = p / 40, j = p - (p / 40) * 40;
        float gx = (j + 0.5f) * (11.f / 40.f) - 0.5f;
        float gy = (i + 0.5f) * (11.f / 40.f) - 0.5f;
        float xin = m0 * gx + m1 * gy + m2;
        float yin = m3 * gx + m4 * gy + m5;
        float x0 = floorf(xin), y0 = floorf(yin);
        float wx = xin - x0, wy = yin - y0;
        int x0i = (int)x0, y0i = (int)y0;
        float v00 = tapf(tp, y0i, x0i),     v01 = tapf(tp, y0i, x0i + 1);
        float v10 = tapf(tp, y0i + 1, x0i), v11 = tapf(tp, y0i + 1, x0i + 1);
        to[p] = v00 * (1.f - wx) * (1.f - wy) + v01 * wx * (1.f - wy) +
                v10 * (1.f - wx) * wy + v11 * wx * wy;
    }
}

// ============ per-sample std stats ============
__global__ __launch_bounds__(TPB) void std_k(const float* __restrict__ x,
                                             float* __restrict__ st) {
    const int b = blockIdx.x;
    const float* xb = x + b * 1600;
    float s = 0.f, s2 = 0.f;
    for (int p = threadIdx.x; p < 1600; p += TPB) {
        float v = xb[p];
        s += v; s2 += v * v;
    }
    s = blockReduceSum(s);
    s2 = blockReduceSum(s2);
    if (threadIdx.x == 0) {
        float mean = s / 1600.f;
        float var = (s2 - 1600.f * mean * mean) / 1599.f;
        float sd = sqrtf(var);
        st[b * 2] = rsqrtf(sd * 6.283185307179586f);   // mult
        st[b * 2 + 1] = -1.f / (2.f * sd * sd);        // pw
    }
}

// ============ mix softmax stats: max + sum over 1600 pixels ============
__global__ __launch_bounds__(TPB) void mix1_k(const float* __restrict__ tt,
                                              const float* __restrict__ dmv,
                                              float* __restrict__ mxs) {
    const int bk = blockIdx.x;
    const float dm = dmv[bk];
    const float* t = tt + (size_t)bk * 1600;
    float mx = -1e30f;
    for (int p = threadIdx.x; p < 1600; p += TPB) mx = fmaxf(mx, dm * t[p]);
    mx = blockReduceMax(mx);
    float s = 0.f;
    for (int p = threadIdx.x; p < 1600; p += TPB) s += expf(dm * t[p] - mx);
    s = blockReduceSum(s);
    if (threadIdx.x == 0) { mxs[bk * 2] = mx; mxs[bk * 2 + 1] = s; }
}

// ============ log-likelihood per sample ============
__global__ __launch_bounds__(TPB) void ll_k(const float* __restrict__ x,
                                            const float* __restrict__ tt,
                                            const float* __restrict__ dmv,
                                            const float* __restrict__ mxs,
                                            const float* __restrict__ st,
                                            float* __restrict__ part) {
    const int b = blockIdx.x;
    __shared__ float dms[24], mxh[24], sih[24];
    if (threadIdx.x < 24) {
        int bk = b * 24 + threadIdx.x;
        dms[threadIdx.x] = dmv[bk];
        mxh[threadIdx.x] = mxs[bk * 2];
        sih[threadIdx.x] = 1.f / mxs[bk * 2 + 1];
    }
    __syncthreads();
    const float mult = st[b * 2], pw = st[b * 2 + 1];
    const float* xb = x + b * 1600;
    const float* tb = tt + (size_t)b * 24 * 1600;
    float acc = 0.f;
    for (int p = threadIdx.x; p < 1600; p += TPB) {
        float xv = xb[p];
        float ssum = 0.f;
        for (int k = 0; k < 24; ++k) {
            float tv = tb[(size_t)k * 1600 + p];
            float dd = xv - tv;
            float g = mult * expf(dd * dd * pw);
            float mixv = expf(dms[k] * tv - mxh[k]) * sih[k];
            ssum += g * mixv;
        }
        acc += logf(ssum);
    }
    acc = blockReduceSum(acc);
    if (threadIdx.x == 0) part[b] = acc;
}

__global__ void fin_k(const float* __restrict__ part, float* __restrict__ out) {
    float v = part[threadIdx.x];   // 64 threads, one wave
#pragma unroll
    for (int o = 32; o > 0; o >>= 1) v += __shfl_down(v, o, 64);
    if (threadIdx.x == 0) out[0] = v * (1.f / 64.f);
}

// ============ launch ============
extern "C" void kernel_launch(void* const* d_in, const int* in_sizes, int n_in,
                              void* d_out, int out_size, void* d_ws, size_t ws_size,
                              hipStream_t stream) {
    const float* x   = (const float*)d_in[0];
    const float* w1  = (const float*)d_in[1];
    const float* b1  = (const float*)d_in[2];
    const float* w2  = (const float*)d_in[3];
    const float* b2  = (const float*)d_in[4];
    const float* w3  = (const float*)d_in[5];
    const float* b3  = (const float*)d_in[6];
    const float* w4  = (const float*)d_in[7];
    const float* b4  = (const float*)d_in[8];
    const float* w5  = (const float*)d_in[9];
    const float* b5  = (const float*)d_in[10];
    const float* tpl = (const float*)d_in[11];
    float* out = (float*)d_out;
    char* W = (char*)d_ws;

    ushort* wt2h = (ushort*)(W + OFFB_W2H);
    ushort* wt2l = (ushort*)(W + OFFB_W2L);
    ushort* wt3h = (ushort*)(W + OFFB_W3H);
    ushort* wt3l = (ushort*)(W + OFFB_W3L);
    ushort* wt4h = (ushort*)(W + OFFB_W4H);
    ushort* wt4l = (ushort*)(W + OFFB_W4L);
    ushort* h1u  = (ushort*)(W + OFFB_H1);
    ushort* h2u  = (ushort*)(W + OFFB_H2);
    ushort* h3u  = (ushort*)(W + OFFB_H3);
    float*  h4f  = (float*)(W + OFFB_H4);
    float*  pose = (float*)(W + OFFB_POSE);
    float*  dmv  = (float*)(W + OFFB_DMV);
    float*  ttb  = (float*)(W + OFFB_TT);
    float*  stv  = (float*)(W + OFFB_ST);
    float*  mxs  = (float*)(W + OFFB_MXS);
    float*  part = (float*)(W + OFFB_PART);

    wprep_k<<<Kc * 128, 128, 0, stream>>>(w2, wt2h, wt2l);
    wprep_k<<<Kc * 128, 128, 0, stream>>>(w3, wt3h, wt3l);
    wprep_k<<<Kc * 128, 128, 0, stream>>>(w4, wt4h, wt4l);
    std_k<<<Bn, TPB, 0, stream>>>(x, stv);

    for (int ch = 0; ch < NCHUNK; ++ch) {
        int bk0 = ch * CH;
        conv1_k<<<CH * P1 * 128 / TPB, TPB, 0, stream>>>(x, w1, b1, h1u, bk0);
        mfconv_k<19, 19, 9, 9, 2, 3, 2, false><<<CH, 192, 0, stream>>>(h1u, wt2h, wt2l, b2, h2u, nullptr, bk0);
        mfconv_k<9, 9, 7, 7, 1, 2, 2, false><<<CH, 128, 0, stream>>>(h2u, wt3h, wt3l, b3, h3u, nullptr, bk0);
        mfconv_k<7, 7, 5, 5, 1, 2, 1, true><<<CH, 128, 0, stream>>>(h3u, wt4h, wt4l, b4, nullptr, h4f, bk0);
        head_k<<<CH, TPB, 0, stream>>>(h4f, w5, b5, tpl, pose, dmv, out, bk0);
    }

    warp_k<<<NBK, TPB, 0, stream>>>(pose, tpl, ttb);
    mix1_k<<<NBK, TPB, 0, stream>>>(ttb, dmv, mxs);
    ll_k<<<Bn, TPB, 0, stream>>>(x, ttb, dmv, mxs, stv, part);
    fin_k<<<1, 64, 0, stream>>>(part, out);
}

// Round 3
// 626.335 us; speedup vs baseline: 4.8661x; 2.3110x over previous
//
#include <hip/hip_runtime.h>
#include <math.h>

#define TPB 256

typedef __attribute__((ext_vector_type(8))) short s16x8;
typedef __attribute__((ext_vector_type(4))) float f32x4;

constexpr int Bn = 64, Kc = 24, TSz = 11;
constexpr int NBK = Bn * Kc;          // 1536
constexpr int CH = 768;               // (b,k) instances per chunk
constexpr int NCHUNK = NBK / CH;      // 2
constexpr int P1 = 361, P2 = 81, P3 = 49, P4 = 25;

// ---- workspace offsets (BYTES) ----
constexpr size_t SZW_B    = (size_t)Kc * 4 * 9 * 128 * 32 * 2;   // 7,077,888 B/plane
constexpr size_t OFFB_W2  = 0;
constexpr size_t OFFB_W3  = OFFB_W2 + SZW_B;
constexpr size_t OFFB_W4  = OFFB_W3 + SZW_B;
constexpr size_t OFFB_H1  = OFFB_W4 + SZW_B;
constexpr size_t OFFB_H2  = OFFB_H1 + (size_t)CH * P1 * 128 * 2;
constexpr size_t OFFB_H3  = OFFB_H2 + (size_t)CH * P2 * 128 * 2;
constexpr size_t OFFB_H4  = OFFB_H3 + (size_t)CH * P3 * 128 * 2;
constexpr size_t OFFB_POSE= OFFB_H4 + (size_t)CH * P4 * 128 * 2;
constexpr size_t OFFB_DMV = OFFB_POSE + (size_t)NBK * 6 * 4;
constexpr size_t OFFB_TT  = OFFB_DMV + (size_t)NBK * 4;
constexpr size_t OFFB_ST  = OFFB_TT + (size_t)NBK * 1600 * 4;
constexpr size_t OFFB_MXS = OFFB_ST + 512;
constexpr size_t OFFB_PART= OFFB_MXS + (size_t)NBK * 2 * 4;

// ---- output offsets (floats) ----
constexpr int OUT_OC = 1;                   // input_ocae [B,K,136]
constexpr int OUT_XM = 1 + NBK * 136;
constexpr int OUT_DM = OUT_XM + NBK * 6;

// ============ bf16 helpers ============
__device__ __forceinline__ ushort f2b(float f) {
    union { float f; unsigned u; } c; c.f = f;
    unsigned r = c.u + 0x7fffu + ((c.u >> 16) & 1u);
    return (ushort)(r >> 16);
}
__device__ __forceinline__ float b2f(ushort h) {
    union { unsigned u; float f; } c; c.u = ((unsigned)h) << 16; return c.f;
}

// ============ reductions (TPB=256 → 4 waves) ============
__device__ __forceinline__ float blockReduceSum(float v) {
    __shared__ float red[4];
    __syncthreads();
#pragma unroll
    for (int o = 32; o > 0; o >>= 1) v += __shfl_down(v, o, 64);
    int lane = threadIdx.x & 63, wv = threadIdx.x >> 6;
    if (lane == 0) red[wv] = v;
    __syncthreads();
    return red[0] + red[1] + red[2] + red[3];
}

__device__ __forceinline__ float blockReduceMax(float v) {
    __shared__ float redm[4];
    __syncthreads();
#pragma unroll
    for (int o = 32; o > 0; o >>= 1) v = fmaxf(v, __shfl_down(v, o, 64));
    int lane = threadIdx.x & 63, wv = threadIdx.x >> 6;
    if (lane == 0) redm[wv] = v;
    __syncthreads();
    return fmaxf(fmaxf(redm[0], redm[1]), fmaxf(redm[2], redm[3]));
}

// ============ weight prep: w[k][cout][cin][tap] f32 -> bf16 [k][cb][tap][cout][32] ============
__global__ __launch_bounds__(128) void wprep_k(const float* __restrict__ w,
                                               ushort* __restrict__ wth) {
    __shared__ float ld[1152];
    const int k = blockIdx.x >> 7, cout = blockIdx.x & 127;
    const float* src = w + (size_t)(k * 128 + cout) * 1152;
    for (int i = threadIdx.x; i < 1152; i += 128) ld[i] = src[i];
    __syncthreads();
    for (int e = threadIdx.x; e < 1152; e += 128) {
        int cb = e / 288, r = e - cb * 288, tap = r / 32, c32 = r - tap * 32;
        int cin = cb * 32 + c32;
        size_t d = (((size_t)(k * 4 + cb) * 9 + tap) * 128 + cout) * 32 + c32;
        wth[d] = f2b(ld[cin * 9 + tap]);
    }
}

// ============ conv1: x[B,1,40,40] -> h1[CH][361][128] bf16, stride 2, relu ============
// one thread = 1 pixel x 8 couts, 16B vector store
__global__ __launch_bounds__(TPB) void conv1_k(const float* __restrict__ x,
                                               const float* __restrict__ w1,
                                               const float* __restrict__ b1,
                                               ushort* __restrict__ h1, int bk0) {
    int idx = blockIdx.x * TPB + threadIdx.x;   // exact: CH*361*16
    int c8 = (idx & 15) * 8;
    int t = idx >> 4;
    int bkL = t / 361;
    int pos = t - bkL * 361;
    int bk = bk0 + bkL;
    int b = bk / Kc, k = bk - b * Kc;
    int y = pos / 19, xx = pos - y * 19;
    const float* xb = x + b * 1600 + (y * 2) * 40 + xx * 2;
    float xt[9];
#pragma unroll
    for (int dy = 0; dy < 3; ++dy)
#pragma unroll
        for (int dx = 0; dx < 3; ++dx) xt[dy * 3 + dx] = xb[dy * 40 + dx];
    const float* wp = w1 + (size_t)(k * 128 + c8) * 9;
    const float* bp = b1 + k * 128 + c8;
    s16x8 v;
#pragma unroll
    for (int j = 0; j < 8; ++j) {
        float s = bp[j];
#pragma unroll
        for (int t9 = 0; t9 < 9; ++t9) s += wp[j * 9 + t9] * xt[t9];
        v[j] = (short)f2b(fmaxf(s, 0.f));
    }
    *(s16x8*)(h1 + ((size_t)t << 7) + c8) = v;
}

// ============ MFMA implicit-GEMM conv: bf16 act x bf16 weights ============
// A (im2col) staged in LDS per 32-cin slab; B direct from global (L1/L2).
// K-order (cb, tap, cin8) identical for A and B -> hw k-permutation cancels.
// grid = (CH, NSPLIT); each block computes 128/NSPLIT couts for one bk.
template <int IH, int IW, int OH, int OW, int ST, int NW, int NSPLIT>
__global__ __launch_bounds__(NW * 64) void mfconv_k(
    const ushort* __restrict__ hin, const ushort* __restrict__ wth,
    const float* __restrict__ bias, ushort* __restrict__ hout, int bk0) {
    constexpr int IP = IH * IW, OP = OH * OW, NF = 8 / NSPLIT;
    __shared__ ushort As[IP * 40];     // row stride 40 bf16 (80B)
    const int bkL = blockIdx.x;
    const int cout0 = blockIdx.y * (128 / NSPLIT);
    const int k = (bk0 + bkL) % Kc;
    const int tid = threadIdx.x;
    const int wv = tid >> 6, l = tid & 63, l16 = l & 15, g = l >> 4;
    constexpr int NT = NW * 64;

    f32x4 acc[NF];
#pragma unroll
    for (int n = 0; n < NF; ++n) acc[n] = (f32x4)0.f;

    int opix0 = wv * 16 + l16;
    int opc = opix0 < OP ? opix0 : OP - 1;     // clamp pad rows
    int oy = opc / OW, ox = opc - oy * OW;
    const int ibase = oy * ST * IW + ox * ST;
    const ushort* hsrc = hin + (size_t)bkL * IP * 128;

    for (int cb = 0; cb < 4; ++cb) {
        __syncthreads();
        for (int i = tid; i < IP * 4; i += NT) {
            int row = i >> 2, gc = i & 3;
            s16x8 v = *(const s16x8*)(hsrc + row * 128 + cb * 32 + gc * 8);
            *(s16x8*)(As + row * 40 + 8 * (gc ^ ((row >> 3) & 1))) = v;
        }
        __syncthreads();
        const ushort* wb = wth + ((size_t)(k * 4 + cb) * 9) * 4096 + (cout0 + l16) * 32 + g * 8;
        for (int tap = 0; tap < 9; ++tap) {
            const int ip = ibase + (tap / 3) * IW + (tap % 3);
            s16x8 a = *(const s16x8*)(As + ip * 40 + 8 * (g ^ ((ip >> 3) & 1)));
            const ushort* ph = wb + tap * 4096;
#pragma unroll
            for (int n = 0; n < NF; ++n) {
                s16x8 bh = *(const s16x8*)(ph + n * 512);
                acc[n] = __builtin_amdgcn_mfma_f32_16x16x32_bf16(a, bh, acc[n], 0, 0, 0);
            }
        }
    }
    // epilogue: C/D map col=lane&15, row=(lane>>4)*4+r (m89-verified)
#pragma unroll
    for (int n = 0; n < NF; ++n) {
        int cout = cout0 + n * 16 + l16;
        float bv = bias[k * 128 + cout];
#pragma unroll
        for (int r = 0; r < 4; ++r) {
            int opix = wv * 16 + g * 4 + r;
            if (opix < OP) {
                float v = fmaxf(acc[n][r] + bv, 0.f);
                hout[((size_t)bkL * OP + opix) * 128 + cout] = f2b(v);
            }
        }
    }
}

// ============ conv5 (1x1) + attention + pooling + heads + ocae assembly ============
__global__ __launch_bounds__(TPB) void head_k(const ushort* __restrict__ h4,
                                              const float* __restrict__ w5,
                                              const float* __restrict__ b5,
                                              const float* __restrict__ tpl,
                                              float* __restrict__ pose,
                                              float* __restrict__ dmv,
                                              float* __restrict__ out, int bk0) {
    __shared__ float h4s[128 * 25];   // [c][pix]
    __shared__ float outs[16 * 25];   // [f][pix]
    __shared__ float atts[25];
    __shared__ float pooled[16];
    const int bk = bk0 + blockIdx.x;
    const int k = bk % Kc;
    const ushort* hb = h4 + (size_t)blockIdx.x * 25 * 128;
    for (int i = threadIdx.x; i < 25 * 128; i += TPB) {
        int pix = i >> 7, c = i & 127;
        h4s[c * 25 + pix] = b2f(hb[i]);
    }
    __syncthreads();
    for (int t = threadIdx.x; t < 400; t += TPB) {
        int f = t / 25, pix = t - f * 25;
        const float* wp = w5 + (size_t)(k * 16 + f) * 128;
        float s = b5[k * 16 + f];
        for (int c = 0; c < 128; ++c) s += wp[c] * h4s[c * 25 + pix];
        outs[t] = s;
    }
    __syncthreads();
    if (threadIdx.x < 25) {
        int y5 = threadIdx.x / 5;
        const float* row = outs + 15 * 25 + y5 * 5;
        float mx = row[0];
#pragma unroll
        for (int j = 1; j < 5; ++j) mx = fmaxf(mx, row[j]);
        float ssum = 0.f;
#pragma unroll
        for (int j = 0; j < 5; ++j) ssum += expf(row[j] - mx);
        atts[threadIdx.x] = expf(outs[15 * 25 + threadIdx.x] - mx) / ssum;
    }
    __syncthreads();
    if (threadIdx.x < 15) {
        float s = 0.f;
        const float* row = outs + threadIdx.x * 25;
#pragma unroll
        for (int p = 0; p < 25; ++p) s += row[p] * atts[p];
        pooled[threadIdx.x] = s;
    }
    __syncthreads();
    float* oc = out + OUT_OC + (size_t)bk * 136;
    if (threadIdx.x < 6) {
        float v = fmaxf(pooled[threadIdx.x], 0.f);
        pose[bk * 6 + threadIdx.x] = v;
        oc[1 + threadIdx.x] = v;
        out[OUT_XM + bk * 6 + threadIdx.x] = v;
    } else if (threadIdx.x == 6) {
        float d = 1.f / (1.f + expf(-pooled[6]));
        dmv[bk] = d;
        oc[0] = d;
        out[OUT_DM + bk] = d;
    } else if (threadIdx.x >= 7 && threadIdx.x < 15) {
        oc[128 + threadIdx.x - 7] = fmaxf(pooled[threadIdx.x], 0.f);
    }
    for (int t = threadIdx.x; t < 121; t += TPB) oc[7 + t] = tpl[k * 121 + t];
}

// ============ affine warp + bilinear TS->40x40, fused mix-softmax stats ============
__device__ __forceinline__ float tapf(const float* tp, int y, int x) {
    bool valid = (x >= 0) && (x < TSz) && (y >= 0) && (y < TSz);
    int yc = min(max(y, 0), TSz - 1), xc = min(max(x, 0), TSz - 1);
    float v = tp[yc * TSz + xc];
    return valid ? v : 0.f;
}

__global__ __launch_bounds__(TPB) void warp_mix_k(const float* __restrict__ pose,
                                                  const float* __restrict__ tpl,
                                                  const float* __restrict__ dmv,
                                                  float* __restrict__ tt,
                                                  float* __restrict__ mxs) {
    __shared__ float tp[121];
    const int bk = blockIdx.x, k = bk % Kc;
    for (int i = threadIdx.x; i < 121; i += TPB) tp[i] = tpl[k * 121 + i];
    const float* ps = pose + bk * 6;
    const float D2R = 0.017453292519943295f;
    float ang = ps[0] * D2R, tx = ps[1], ty = ps[2];
    float sc = fmaxf(ps[3], 1e-2f);
    float shx = ps[4] * D2R, shy = ps[5] * D2R;
    float cams = cosf(ang - shy), sams = sinf(ang - shy);
    float cshy = cosf(shy), tshx = tanf(shx);
    float av = cams / cshy;
    float bv = -cams * tshx / cshy - sinf(ang);
    float cv = sams / cshy;
    float dv = -sams * tshx / cshy + cosf(ang);
    float m0 = dv / sc, m1 = -bv / sc, m3 = -cv / sc, m4 = av / sc;
    float m2 = m0 * (-5.f - tx) + m1 * (-5.f - ty) + 5.f;
    float m5 = m3 * (-5.f - tx) + m4 * (-5.f - ty) + 5.f;
    __syncthreads();
    float* to = tt + (size_t)bk * 1600;
    float tvl[7];
#pragma unroll
    for (int r = 0; r < 7; ++r) {
        int p = threadIdx.x + r * TPB;
        float val = 0.f;
        if (p < 1600) {
            int i = p / 40, j = p - (p / 40) * 40;
            float gx = (j + 0.5f) * (11.f / 40.f) - 0.5f;
            float gy = (i + 0.5f) * (11.f / 40.f) - 0.5f;
            float xin = m0 * gx + m1 * gy + m2;
            float yin = m3 * gx + m4 * gy + m5;
            float x0 = floorf(xin), y0 = floorf(yin);
            float wx = xin - x0, wy = yin - y0;
            int x0i = (int)x0, y0i = (int)y0;
            float v00 = tapf(tp, y0i, x0i),     v01 = tapf(tp, y0i, x0i + 1);
            float v10 = tapf(tp, y0i + 1, x0i), v11 = tapf(tp, y0i + 1, x0i + 1);
            val = v00 * (1.f - wx) * (1.f - wy) + v01 * wx * (1.f - wy) +
                  v10 * (1.f - wx) * wy + v11 * wx * wy;
            to[p] = val;
        }
        tvl[r] = val;
    }
    const float dm = dmv[bk];
    float mx = -1e30f;
#pragma unroll
    for (int r = 0; r < 7; ++r) {
        int p = threadIdx.x + r * TPB;
        if (p < 1600) mx = fmaxf(mx, dm * tvl[r]);
    }
    mx = blockReduceMax(mx);
    float s = 0.f;
#pragma unroll
    for (int r = 0; r < 7; ++r) {
        int p = threadIdx.x + r * TPB;
        if (p < 1600) s += expf(dm * tvl[r] - mx);
    }
    s = blockReduceSum(s);
    if (threadIdx.x == 0) { mxs[bk * 2] = mx; mxs[bk * 2 + 1] = s; }
}

// ============ per-sample std stats ============
__global__ __launch_bounds__(TPB) void std_k(const float* __restrict__ x,
                                             float* __restrict__ st) {
    const int b = blockIdx.x;
    const float* xb = x + b * 1600;
    float s = 0.f, s2 = 0.f;
    for (int p = threadIdx.x; p < 1600; p += TPB) {
        float v = xb[p];
        s += v; s2 += v * v;
    }
    s = blockReduceSum(s);
    s2 = blockReduceSum(s2);
    if (threadIdx.x == 0) {
        float mean = s / 1600.f;
        float var = (s2 - 1600.f * mean * mean) / 1599.f;
        float sd = sqrtf(var);
        st[b * 2] = rsqrtf(sd * 6.283185307179586f);   // mult
        st[b * 2 + 1] = -1.f / (2.f * sd * sd);        // pw
    }
}

// ============ log-likelihood, split over 4 pixel-blocks per sample ============
__global__ __launch_bounds__(TPB) void ll_k(const float* __restrict__ x,
                                            const float* __restrict__ tt,
                                            const float* __restrict__ dmv,
                                            const float* __restrict__ mxs,
                                            const float* __restrict__ st,
                                            float* __restrict__ part) {
    const int b = blockIdx.x, sp = blockIdx.y;
    __shared__ float dms[24], mxh[24], sih[24];
    if (threadIdx.x < 24) {
        int bk = b * 24 + threadIdx.x;
        dms[threadIdx.x] = dmv[bk];
        mxh[threadIdx.x] = mxs[bk * 2];
        sih[threadIdx.x] = 1.f / mxs[bk * 2 + 1];
    }
    __syncthreads();
    const float mult = st[b * 2], pw = st[b * 2 + 1];
    const float* xb = x + b * 1600;
    const float* tb = tt + (size_t)b * 24 * 1600;
    float acc = 0.f;
    for (int p = sp * 400 + threadIdx.x; p < sp * 400 + 400; p += TPB) {
        float xv = xb[p];
        float ssum = 0.f;
        for (int k = 0; k < 24; ++k) {
            float tv = tb[(size_t)k * 1600 + p];
            float dd = xv - tv;
            float g = mult * expf(dd * dd * pw);
            float mixv = expf(dms[k] * tv - mxh[k]) * sih[k];
            ssum += g * mixv;
        }
        acc += logf(ssum);
    }
    acc = blockReduceSum(acc);
    if (threadIdx.x == 0) part[b * 4 + sp] = acc;
}

__global__ void fin_k(const float* __restrict__ part, float* __restrict__ out) {
    float v = part[threadIdx.x * 4] + part[threadIdx.x * 4 + 1] +
              part[threadIdx.x * 4 + 2] + part[threadIdx.x * 4 + 3];
#pragma unroll
    for (int o = 32; o > 0; o >>= 1) v += __shfl_down(v, o, 64);
    if (threadIdx.x == 0) out[0] = v * (1.f / 64.f);
}

// ============ launch ============
extern "C" void kernel_launch(void* const* d_in, const int* in_sizes, int n_in,
                              void* d_out, int out_size, void* d_ws, size_t ws_size,
                              hipStream_t stream) {
    const float* x   = (const float*)d_in[0];
    const float* w1  = (const float*)d_in[1];
    const float* b1  = (const float*)d_in[2];
    const float* w2  = (const float*)d_in[3];
    const float* b2  = (const float*)d_in[4];
    const float* w3  = (const float*)d_in[5];
    const float* b3  = (const float*)d_in[6];
    const float* w4  = (const float*)d_in[7];
    const float* b4  = (const float*)d_in[8];
    const float* w5  = (const float*)d_in[9];
    const float* b5  = (const float*)d_in[10];
    const float* tpl = (const float*)d_in[11];
    float* out = (float*)d_out;
    char* W = (char*)d_ws;

    ushort* wt2 = (ushort*)(W + OFFB_W2);
    ushort* wt3 = (ushort*)(W + OFFB_W3);
    ushort* wt4 = (ushort*)(W + OFFB_W4);
    ushort* h1u = (ushort*)(W + OFFB_H1);
    ushort* h2u = (ushort*)(W + OFFB_H2);
    ushort* h3u = (ushort*)(W + OFFB_H3);
    ushort* h4u = (ushort*)(W + OFFB_H4);
    float*  pose = (float*)(W + OFFB_POSE);
    float*  dmv  = (float*)(W + OFFB_DMV);
    float*  ttb  = (float*)(W + OFFB_TT);
    float*  stv  = (float*)(W + OFFB_ST);
    float*  mxs  = (float*)(W + OFFB_MXS);
    float*  part = (float*)(W + OFFB_PART);

    wprep_k<<<Kc * 128, 128, 0, stream>>>(w2, wt2);
    wprep_k<<<Kc * 128, 128, 0, stream>>>(w3, wt3);
    wprep_k<<<Kc * 128, 128, 0, stream>>>(w4, wt4);
    std_k<<<Bn, TPB, 0, stream>>>(x, stv);

    for (int ch = 0; ch < NCHUNK; ++ch) {
        int bk0 = ch * CH;
        conv1_k<<<CH * 361 * 16 / TPB, TPB, 0, stream>>>(x, w1, b1, h1u, bk0);
        mfconv_k<19, 19, 9, 9, 2, 6, 1><<<dim3(CH, 1), 384, 0, stream>>>(h1u, wt2, b2, h2u, bk0);
        mfconv_k<9, 9, 7, 7, 1, 4, 2><<<dim3(CH, 2), 256, 0, stream>>>(h2u, wt3, b3, h3u, bk0);
        mfconv_k<7, 7, 5, 5, 1, 2, 2><<<dim3(CH, 2), 128, 0, stream>>>(h3u, wt4, b4, h4u, bk0);
        head_k<<<CH, TPB, 0, stream>>>(h4u, w5, b5, tpl, pose, dmv, out, bk0);
    }

    warp_mix_k<<<NBK, TPB, 0, stream>>>(pose, tpl, dmv, ttb, mxs);
    ll_k<<<dim3(Bn, 4), TPB, 0, stream>>>(x, ttb, dmv, mxs, stv, part);
    fin_k<<<1, 64, 0, stream>>>(part, out);
}

// Round 4
// 436.710 us; speedup vs baseline: 6.9791x; 1.4342x over previous
//
#include <hip/hip_runtime.h>
#include <math.h>

#define TPB 256

typedef __attribute__((ext_vector_type(8))) short s16x8;
typedef __attribute__((ext_vector_type(4))) float f32x4;
typedef unsigned int u32;

constexpr int Bn = 64, Kc = 24, TSz = 11;
constexpr int NBK = Bn * Kc;          // 1536
constexpr int CH = 768;               // (b,k) instances per chunk
constexpr int NCHUNK = NBK / CH;      // 2
constexpr int P1 = 361, P2 = 81, P3 = 49, P4 = 25;

// ---- workspace offsets (BYTES) ----
constexpr size_t SZW_B    = (size_t)Kc * 36 * 4096 * 2;      // 7,077,888 B/plane
constexpr size_t OFFB_W2  = 0;
constexpr size_t OFFB_W3  = OFFB_W2 + SZW_B;
constexpr size_t OFFB_W4  = OFFB_W3 + SZW_B;
constexpr size_t OFFB_H1  = OFFB_W4 + SZW_B;
constexpr size_t OFFB_H2  = OFFB_H1 + (size_t)CH * P1 * 128 * 2;
constexpr size_t OFFB_H3  = OFFB_H2 + (size_t)CH * P2 * 128 * 2;
constexpr size_t OFFB_H4  = OFFB_H3 + (size_t)CH * P3 * 128 * 2;
constexpr size_t OFFB_POSE= OFFB_H4 + (size_t)CH * P4 * 128 * 2;
constexpr size_t OFFB_DMV = OFFB_POSE + (size_t)NBK * 6 * 4;
constexpr size_t OFFB_TT  = OFFB_DMV + (size_t)NBK * 4;
constexpr size_t OFFB_ST  = OFFB_TT + (size_t)NBK * 1600 * 4;
constexpr size_t OFFB_MXS = OFFB_ST + 512;
constexpr size_t OFFB_PART= OFFB_MXS + (size_t)NBK * 2 * 4;

// ---- output offsets (floats) ----
constexpr int OUT_OC = 1;                   // input_ocae [B,K,136]
constexpr int OUT_XM = 1 + NBK * 136;
constexpr int OUT_DM = OUT_XM + NBK * 6;

// ============ bf16 helpers ============
__device__ __forceinline__ ushort f2b(float f) {
    union { float f; unsigned u; } c; c.f = f;
    unsigned r = c.u + 0x7fffu + ((c.u >> 16) & 1u);
    return (ushort)(r >> 16);
}
__device__ __forceinline__ float b2f(ushort h) {
    union { unsigned u; float f; } c; c.u = ((unsigned)h) << 16; return c.f;
}

__device__ __forceinline__ void gload_lds16(const ushort* g, ushort* l) {
    __builtin_amdgcn_global_load_lds((const u32*)g, (u32*)l, 16, 0, 0);
}

// ============ reductions (TPB=256 → 4 waves) ============
__device__ __forceinline__ float blockReduceSum(float v) {
    __shared__ float red[4];
    __syncthreads();
#pragma unroll
    for (int o = 32; o > 0; o >>= 1) v += __shfl_down(v, o, 64);
    int lane = threadIdx.x & 63, wv = threadIdx.x >> 6;
    if (lane == 0) red[wv] = v;
    __syncthreads();
    return red[0] + red[1] + red[2] + red[3];
}

__device__ __forceinline__ float blockReduceMax(float v) {
    __shared__ float redm[4];
    __syncthreads();
#pragma unroll
    for (int o = 32; o > 0; o >>= 1) v = fmaxf(v, __shfl_down(v, o, 64));
    int lane = threadIdx.x & 63, wv = threadIdx.x >> 6;
    if (lane == 0) redm[wv] = v;
    __syncthreads();
    return fmaxf(fmaxf(redm[0], redm[1]), fmaxf(redm[2], redm[3]));
}

// ============ weight prep: w[k][cout][cin][tap] f32 -> bf16 frag-major ============
// dst: [k][cb][tap] blocks of 4096 ush, inner [n][g][l16][e]  (n=cout/16, l16=cout%16,
// g=c32/8, e=c32%8) — so the 8 KB tap-slab is LINEAR in the LDS frag layout.
__global__ __launch_bounds__(128) void wprep_k(const float* __restrict__ w,
                                               ushort* __restrict__ wt) {
    __shared__ float ld[1152];
    const int k = blockIdx.x >> 7, cout = blockIdx.x & 127;
    const float* src = w + (size_t)(k * 128 + cout) * 1152;
    for (int i = threadIdx.x; i < 1152; i += 128) ld[i] = src[i];
    __syncthreads();
    const int n = cout >> 4, l16 = cout & 15;
    for (int e = threadIdx.x; e < 1152; e += 128) {
        int cb = e / 288, r = e - cb * 288, tap = r >> 5, c32 = r & 31;
        int cin = cb * 32 + c32;
        size_t d = (size_t)((k * 4 + cb) * 9 + tap) * 4096
                 + n * 512 + (c32 >> 3) * 128 + l16 * 8 + (c32 & 7);
        wt[d] = f2b(ld[cin * 9 + tap]);
    }
}

// ============ conv1: x[B,1,40,40] -> h1[CH][361][128] bf16, stride 2, relu ============
__global__ __launch_bounds__(TPB) void conv1_k(const float* __restrict__ x,
                                               const float* __restrict__ w1,
                                               const float* __restrict__ b1,
                                               ushort* __restrict__ h1, int bk0) {
    int idx = blockIdx.x * TPB + threadIdx.x;   // exact: CH*361*16
    int c8 = (idx & 15) * 8;
    int t = idx >> 4;
    int bkL = t / 361;
    int pos = t - bkL * 361;
    int bk = bk0 + bkL;
    int b = bk / Kc, k = bk - b * Kc;
    int y = pos / 19, xx = pos - y * 19;
    const float* xb = x + b * 1600 + (y * 2) * 40 + xx * 2;
    float xt[9];
#pragma unroll
    for (int dy = 0; dy < 3; ++dy)
#pragma unroll
        for (int dx = 0; dx < 3; ++dx) xt[dy * 3 + dx] = xb[dy * 40 + dx];
    const float* wp = w1 + (size_t)(k * 128 + c8) * 9;
    const float* bp = b1 + k * 128 + c8;
    s16x8 v;
#pragma unroll
    for (int j = 0; j < 8; ++j) {
        float s = bp[j];
#pragma unroll
        for (int t9 = 0; t9 < 9; ++t9) s += wp[j * 9 + t9] * xt[t9];
        v[j] = (short)f2b(fmaxf(s, 0.f));
    }
    *(s16x8*)(h1 + ((size_t)t << 7) + c8) = v;
}

// ============ MFMA implicit-GEMM conv ============
// Block = (k, IBK b's). 4 waves = 2 m-groups x 2 n-groups; wave = MW m-frags x 4 n-frags
// (register B/A reuse). A input-patch in LDS (stride-40 rows, XOR chunk swizzle).
// B (weights) double-buffered in LDS via global_load_lds w16, prefetched 1 tap ahead.
// Grid k-clustered per XCD: i -> xcd=i&7, k=xcd*3+(i>>3)%3 (L2 sees 3 weight slabs).
template <int IH, int IW, int OH, int OW, int ST, int IBK, int MW>
__global__ __launch_bounds__(256) void mfconv_k(
    const ushort* __restrict__ hin, const ushort* __restrict__ wt,
    const float* __restrict__ bias, ushort* __restrict__ hout) {
    constexpr int IP = IH * IW, OP = OH * OW, MR = IBK * OP;
    __shared__ ushort As[IBK * IP * 40];
    __shared__ ushort Bs[2 * 4096];
    const int bi = blockIdx.x;
    const int xcd = bi & 7, j = bi >> 3;
    const int k = xcd * 3 + j % 3, grp = j / 3;
    const int bkL0 = (grp * IBK) * 24 + k;
    const int tid = threadIdx.x;
    const int w = tid >> 6, l = tid & 63, l16 = l & 15, g = l >> 4;
    const int mgrp = w >> 1, ngrp = w & 1;
    const ushort* wk = wt + (size_t)k * 36 * 4096;

    f32x4 acc[MW][4];
#pragma unroll
    for (int m = 0; m < MW; ++m)
#pragma unroll
        for (int n = 0; n < 4; ++n) acc[m][n] = (f32x4)0.f;

    int ibase[MW];
#pragma unroll
    for (int m = 0; m < MW; ++m) {
        int row = (mgrp * MW + m) * 16 + l16;
        row = row < MR ? row : MR - 1;
        int b = row / OP, pix = row - b * OP;
        int oy = pix / OW, ox = pix - oy * OW;
        ibase[m] = b * IP + oy * ST * IW + ox * ST;
    }

    // initial B prefetch (cb=0, tap=0) into buf 0
    {
        const int sl = w * 2;
        gload_lds16(wk + sl * 512 + l * 8, Bs + sl * 512);
        gload_lds16(wk + (sl + 1) * 512 + l * 8, Bs + (sl + 1) * 512);
    }

    for (int cb = 0; cb < 4; ++cb) {
        // stage A slab (32 cins) for all IBK patches
        for (int t = tid; t < IBK * IP * 4; t += 256) {
            int row = t >> 2, gc = t & 3;
            int b = row / IP, ipx = row - b * IP;
            s16x8 v = *(const s16x8*)(hin + ((size_t)(bkL0 + b * 24) * IP + ipx) * 128 + cb * 32 + gc * 8);
            *(s16x8*)(As + row * 40 + 8 * (gc ^ ((row >> 3) & 1))) = v;
        }
        __syncthreads();
#pragma unroll
        for (int tap = 0; tap < 9; ++tap) {
            const int it = cb * 9 + tap;
            const ushort* Bc = Bs + (it & 1) * 4096;
            if (it < 35) {      // prefetch next tap's 8 KB into other buffer
                ushort* Bnx = Bs + ((it & 1) ^ 1) * 4096;
                const ushort* src = wk + (size_t)(it + 1) * 4096;
                const int sl = w * 2;
                gload_lds16(src + sl * 512 + l * 8, Bnx + sl * 512);
                gload_lds16(src + (sl + 1) * 512 + l * 8, Bnx + (sl + 1) * 512);
            }
            const int ioff = (tap / 3) * IW + (tap % 3);
            s16x8 a[MW];
#pragma unroll
            for (int m = 0; m < MW; ++m) {
                int ip = ibase[m] + ioff;
                a[m] = *(const s16x8*)(As + ip * 40 + 8 * (g ^ ((ip >> 3) & 1)));
            }
#pragma unroll
            for (int n = 0; n < 4; ++n) {
                s16x8 bb = *(const s16x8*)(Bc + (ngrp * 4 + n) * 512 + g * 128 + l16 * 8);
#pragma unroll
                for (int m = 0; m < MW; ++m)
                    acc[m][n] = __builtin_amdgcn_mfma_f32_16x16x32_bf16(a[m], bb, acc[m][n], 0, 0, 0);
            }
            __syncthreads();
        }
    }
    // epilogue: C/D map col=lane&15, row=(lane>>4)*4+r
#pragma unroll
    for (int n = 0; n < 4; ++n) {
        int cout = (ngrp * 4 + n) * 16 + l16;
        float bv = bias[k * 128 + cout];
#pragma unroll
        for (int m = 0; m < MW; ++m) {
#pragma unroll
            for (int r = 0; r < 4; ++r) {
                int row = (mgrp * MW + m) * 16 + g * 4 + r;
                if (row < MR) {
                    int b = row / OP, opix = row - b * OP;
                    float v2 = fmaxf(acc[m][n][r] + bv, 0.f);
                    hout[((size_t)(bkL0 + b * 24) * OP + opix) * 128 + cout] = f2b(v2);
                }
            }
        }
    }
}

// ============ conv5 (1x1) + attention + pooling + heads + ocae assembly ============
__global__ __launch_bounds__(TPB) void head_k(const ushort* __restrict__ h4,
                                              const float* __restrict__ w5,
                                              const float* __restrict__ b5,
                                              const float* __restrict__ tpl,
                                              float* __restrict__ pose,
                                              float* __restrict__ dmv,
                                              float* __restrict__ out, int bk0) {
    __shared__ float h4s[128 * 25];   // [c][pix]
    __shared__ float outs[16 * 25];   // [f][pix]
    __shared__ float atts[25];
    __shared__ float pooled[16];
    const int bk = bk0 + blockIdx.x;
    const int k = bk % Kc;
    const ushort* hb = h4 + (size_t)blockIdx.x * 25 * 128;
    for (int i = threadIdx.x; i < 25 * 128; i += TPB) {
        int pix = i >> 7, c = i & 127;
        h4s[c * 25 + pix] = b2f(hb[i]);
    }
    __syncthreads();
    for (int t = threadIdx.x; t < 400; t += TPB) {
        int f = t / 25, pix = t - f * 25;
        const float* wp = w5 + (size_t)(k * 16 + f) * 128;
        float s = b5[k * 16 + f];
        for (int c = 0; c < 128; ++c) s += wp[c] * h4s[c * 25 + pix];
        outs[t] = s;
    }
    __syncthreads();
    if (threadIdx.x < 25) {
        int y5 = threadIdx.x / 5;
        const float* row = outs + 15 * 25 + y5 * 5;
        float mx = row[0];
#pragma unroll
        for (int j = 1; j < 5; ++j) mx = fmaxf(mx, row[j]);
        float ssum = 0.f;
#pragma unroll
        for (int j = 0; j < 5; ++j) ssum += expf(row[j] - mx);
        atts[threadIdx.x] = expf(outs[15 * 25 + threadIdx.x] - mx) / ssum;
    }
    __syncthreads();
    if (threadIdx.x < 15) {
        float s = 0.f;
        const float* row = outs + threadIdx.x * 25;
#pragma unroll
        for (int p = 0; p < 25; ++p) s += row[p] * atts[p];
        pooled[threadIdx.x] = s;
    }
    __syncthreads();
    float* oc = out + OUT_OC + (size_t)bk * 136;
    if (threadIdx.x < 6) {
        float v = fmaxf(pooled[threadIdx.x], 0.f);
        pose[bk * 6 + threadIdx.x] = v;
        oc[1 + threadIdx.x] = v;
        out[OUT_XM + bk * 6 + threadIdx.x] = v;
    } else if (threadIdx.x == 6) {
        float d = 1.f / (1.f + expf(-pooled[6]));
        dmv[bk] = d;
        oc[0] = d;
        out[OUT_DM + bk] = d;
    } else if (threadIdx.x >= 7 && threadIdx.x < 15) {
        oc[128 + threadIdx.x - 7] = fmaxf(pooled[threadIdx.x], 0.f);
    }
    for (int t = threadIdx.x; t < 121; t += TPB) oc[7 + t] = tpl[k * 121 + t];
}

// ============ affine warp + bilinear TS->40x40, fused mix-softmax stats ============
__device__ __forceinline__ float tapf(const float* tp, int y, int x) {
    bool valid = (x >= 0) && (x < TSz) && (y >= 0) && (y < TSz);
    int yc = min(max(y, 0), TSz - 1), xc = min(max(x, 0), TSz - 1);
    float v = tp[yc * TSz + xc];
    return valid ? v : 0.f;
}

__global__ __launch_bounds__(TPB) void warp_mix_k(const float* __restrict__ pose,
                                                  const float* __restrict__ tpl,
                                                  const float* __restrict__ dmv,
                                                  float* __restrict__ tt,
                                                  float* __restrict__ mxs) {
    __shared__ float tp[121];
    const int bk = blockIdx.x, k = bk % Kc;
    for (int i = threadIdx.x; i < 121; i += TPB) tp[i] = tpl[k * 121 + i];
    const float* ps = pose + bk * 6;
    const float D2R = 0.017453292519943295f;
    float ang = ps[0] * D2R, tx = ps[1], ty = ps[2];
    float sc = fmaxf(ps[3], 1e-2f);
    float shx = ps[4] * D2R, shy = ps[5] * D2R;
    float cams = cosf(ang - shy), sams = sinf(ang - shy);
    float cshy = cosf(shy), tshx = tanf(shx);
    float av = cams / cshy;
    float bv = -cams * tshx / cshy - sinf(ang);
    float cv = sams / cshy;
    float dv = -sams * tshx / cshy + cosf(ang);
    float m0 = dv / sc, m1 = -bv / sc, m3 = -cv / sc, m4 = av / sc;
    float m2 = m0 * (-5.f - tx) + m1 * (-5.f - ty) + 5.f;
    float m5 = m3 * (-5.f - tx) + m4 * (-5.f - ty) + 5.f;
    __syncthreads();
    float* to = tt + (size_t)bk * 1600;
    float tvl[7];
#pragma unroll
    for (int r = 0; r < 7; ++r) {
        int p = threadIdx.x + r * TPB;
        float val = 0.f;
        if (p < 1600) {
            int i = p / 40, jx = p - (p / 40) * 40;
            float gx = (jx + 0.5f) * (11.f / 40.f) - 0.5f;
            float gy = (i + 0.5f) * (11.f / 40.f) - 0.5f;
            float xin = m0 * gx + m1 * gy + m2;
            float yin = m3 * gx + m4 * gy + m5;
            float x0 = floorf(xin), y0 = floorf(yin);
            float wx = xin - x0, wy = yin - y0;
            int x0i = (int)x0, y0i = (int)y0;
            float v00 = tapf(tp, y0i, x0i),     v01 = tapf(tp, y0i, x0i + 1);
            float v10 = tapf(tp, y0i + 1, x0i), v11 = tapf(tp, y0i + 1, x0i + 1);
            val = v00 * (1.f - wx) * (1.f - wy) + v01 * wx * (1.f - wy) +
                  v10 * (1.f - wx) * wy + v11 * wx * wy;
            to[p] = val;
        }
        tvl[r] = val;
    }
    const float dm = dmv[bk];
    float mx = -1e30f;
#pragma unroll
    for (int r = 0; r < 7; ++r) {
        int p = threadIdx.x + r * TPB;
        if (p < 1600) mx = fmaxf(mx, dm * tvl[r]);
    }
    mx = blockReduceMax(mx);
    float s = 0.f;
#pragma unroll
    for (int r = 0; r < 7; ++r) {
        int p = threadIdx.x + r * TPB;
        if (p < 1600) s += expf(dm * tvl[r] - mx);
    }
    s = blockReduceSum(s);
    if (threadIdx.x == 0) { mxs[bk * 2] = mx; mxs[bk * 2 + 1] = s; }
}

// ============ per-sample std stats ============
__global__ __launch_bounds__(TPB) void std_k(const float* __restrict__ x,
                                             float* __restrict__ st) {
    const int b = blockIdx.x;
    const float* xb = x + b * 1600;
    float s = 0.f, s2 = 0.f;
    for (int p = threadIdx.x; p < 1600; p += TPB) {
        float v = xb[p];
        s += v; s2 += v * v;
    }
    s = blockReduceSum(s);
    s2 = blockReduceSum(s2);
    if (threadIdx.x == 0) {
        float mean = s / 1600.f;
        float var = (s2 - 1600.f * mean * mean) / 1599.f;
        float sd = sqrtf(var);
        st[b * 2] = rsqrtf(sd * 6.283185307179586f);   // mult
        st[b * 2 + 1] = -1.f / (2.f * sd * sd);        // pw
    }
}

// ============ log-likelihood, split over 8 pixel-blocks per sample ============
__global__ __launch_bounds__(TPB) void ll_k(const float* __restrict__ x,
                                            const float* __restrict__ tt,
                                            const float* __restrict__ dmv,
                                            const float* __restrict__ mxs,
                                            const float* __restrict__ st,
                                            float* __restrict__ part) {
    const int b = blockIdx.x, sp = blockIdx.y;
    __shared__ float dms[24], mxh[24], sih[24];
    if (threadIdx.x < 24) {
        int bk = b * 24 + threadIdx.x;
        dms[threadIdx.x] = dmv[bk];
        mxh[threadIdx.x] = mxs[bk * 2];
        sih[threadIdx.x] = 1.f / mxs[bk * 2 + 1];
    }
    __syncthreads();
    const float mult = st[b * 2], pw = st[b * 2 + 1];
    const float* xb = x + b * 1600;
    const float* tb = tt + (size_t)b * 24 * 1600;
    float acc = 0.f;
    int p = sp * 200 + threadIdx.x;
    if (threadIdx.x < 200) {
        float xv = xb[p];
        float ssum = 0.f;
        for (int k = 0; k < 24; ++k) {
            float tv = tb[(size_t)k * 1600 + p];
            float dd = xv - tv;
            float g = mult * expf(dd * dd * pw);
            float mixv = expf(dms[k] * tv - mxh[k]) * sih[k];
            ssum += g * mixv;
        }
        acc = logf(ssum);
    }
    acc = blockReduceSum(acc);
    if (threadIdx.x == 0) part[b * 8 + sp] = acc;
}

__global__ void fin_k(const float* __restrict__ part, float* __restrict__ out) {
    float v = 0.f;
#pragma unroll
    for (int q = 0; q < 8; ++q) v += part[threadIdx.x * 8 + q];
#pragma unroll
    for (int o = 32; o > 0; o >>= 1) v += __shfl_down(v, o, 64);
    if (threadIdx.x == 0) out[0] = v * (1.f / 64.f);
}

// ============ launch ============
extern "C" void kernel_launch(void* const* d_in, const int* in_sizes, int n_in,
                              void* d_out, int out_size, void* d_ws, size_t ws_size,
                              hipStream_t stream) {
    const float* x   = (const float*)d_in[0];
    const float* w1  = (const float*)d_in[1];
    const float* b1  = (const float*)d_in[2];
    const float* w2  = (const float*)d_in[3];
    const float* b2  = (const float*)d_in[4];
    const float* w3  = (const float*)d_in[5];
    const float* b3  = (const float*)d_in[6];
    const float* w4  = (const float*)d_in[7];
    const float* b4  = (const float*)d_in[8];
    const float* w5  = (const float*)d_in[9];
    const float* b5  = (const float*)d_in[10];
    const float* tpl = (const float*)d_in[11];
    float* out = (float*)d_out;
    char* W = (char*)d_ws;

    ushort* wt2 = (ushort*)(W + OFFB_W2);
    ushort* wt3 = (ushort*)(W + OFFB_W3);
    ushort* wt4 = (ushort*)(W + OFFB_W4);
    ushort* h1u = (ushort*)(W + OFFB_H1);
    ushort* h2u = (ushort*)(W + OFFB_H2);
    ushort* h3u = (ushort*)(W + OFFB_H3);
    ushort* h4u = (ushort*)(W + OFFB_H4);
    float*  pose = (float*)(W + OFFB_POSE);
    float*  dmv  = (float*)(W + OFFB_DMV);
    float*  ttb  = (float*)(W + OFFB_TT);
    float*  stv  = (float*)(W + OFFB_ST);
    float*  mxs  = (float*)(W + OFFB_MXS);
    float*  part = (float*)(W + OFFB_PART);

    wprep_k<<<Kc * 128, 128, 0, stream>>>(w2, wt2);
    wprep_k<<<Kc * 128, 128, 0, stream>>>(w3, wt3);
    wprep_k<<<Kc * 128, 128, 0, stream>>>(w4, wt4);
    std_k<<<Bn, TPB, 0, stream>>>(x, stv);

    for (int ch = 0; ch < NCHUNK; ++ch) {
        int bk0 = ch * CH;
        conv1_k<<<CH * 361 * 16 / TPB, TPB, 0, stream>>>(x, w1, b1, h1u, bk0);
        mfconv_k<19, 19, 9, 9, 2, 1, 3><<<768, 256, 0, stream>>>(h1u, wt2, b2, h2u);
        mfconv_k<9, 9, 7, 7, 1, 2, 4><<<384, 256, 0, stream>>>(h2u, wt3, b3, h3u);
        mfconv_k<7, 7, 5, 5, 1, 2, 2><<<384, 256, 0, stream>>>(h3u, wt4, b4, h4u);
        head_k<<<CH, TPB, 0, stream>>>(h4u, w5, b5, tpl, pose, dmv, out, bk0);
    }

    warp_mix_k<<<NBK, TPB, 0, stream>>>(pose, tpl, dmv, ttb, mxs);
    ll_k<<<dim3(Bn, 8), TPB, 0, stream>>>(x, ttb, dmv, mxs, stv, part);
    fin_k<<<1, 64, 0, stream>>>(part, out);
}

// Round 5
// 314.974 us; speedup vs baseline: 9.6765x; 1.3865x over previous
//
#include <hip/hip_runtime.h>
#include <math.h>

#define TPB 256

typedef __attribute__((ext_vector_type(8))) short s16x8;
typedef __attribute__((ext_vector_type(4))) float f32x4;
typedef unsigned int u32;

constexpr int Bn = 64, Kc = 24, TSz = 11;
constexpr int NBK = Bn * Kc;          // 1536
constexpr int CH = 768;               // (b,k) instances per chunk
constexpr int NCHUNK = NBK / CH;      // 2
constexpr int P1 = 361, P2 = 81, P3 = 49, P4 = 25;

// ---- workspace offsets (BYTES) ----
constexpr size_t SZW_B    = (size_t)Kc * 36 * 4096 * 2;      // 7,077,888 B/plane
constexpr size_t OFFB_W2  = 0;
constexpr size_t OFFB_W3  = OFFB_W2 + SZW_B;
constexpr size_t OFFB_W4  = OFFB_W3 + SZW_B;
constexpr size_t OFFB_H1  = OFFB_W4 + SZW_B;
constexpr size_t OFFB_H2  = OFFB_H1 + (size_t)CH * P1 * 128 * 2;
constexpr size_t OFFB_H3  = OFFB_H2 + (size_t)CH * P2 * 128 * 2;
constexpr size_t OFFB_H4  = OFFB_H3 + (size_t)CH * P3 * 128 * 2;
constexpr size_t OFFB_POSE= OFFB_H4 + (size_t)CH * P4 * 128 * 2;
constexpr size_t OFFB_DMV = OFFB_POSE + (size_t)NBK * 6 * 4;
constexpr size_t OFFB_TT  = OFFB_DMV + (size_t)NBK * 4;
constexpr size_t OFFB_ST  = OFFB_TT + (size_t)NBK * 1600 * 4;
constexpr size_t OFFB_MXS = OFFB_ST + 512;
constexpr size_t OFFB_PART= OFFB_MXS + (size_t)NBK * 2 * 4;

// ---- output offsets (floats) ----
constexpr int OUT_OC = 1;                   // input_ocae [B,K,136]
constexpr int OUT_XM = 1 + NBK * 136;
constexpr int OUT_DM = OUT_XM + NBK * 6;

// ============ bf16 helpers ============
__device__ __forceinline__ ushort f2b(float f) {
    union { float f; unsigned u; } c; c.f = f;
    unsigned r = c.u + 0x7fffu + ((c.u >> 16) & 1u);
    return (ushort)(r >> 16);
}
__device__ __forceinline__ float b2f(ushort h) {
    union { unsigned u; float f; } c; c.u = ((unsigned)h) << 16; return c.f;
}

__device__ __forceinline__ void gload_lds16(const ushort* g, ushort* l) {
    __builtin_amdgcn_global_load_lds((const u32*)g, (u32*)l, 16, 0, 0);
}

// ============ reductions (TPB=256 → 4 waves) ============
__device__ __forceinline__ float blockReduceSum(float v) {
    __shared__ float red[4];
    __syncthreads();
#pragma unroll
    for (int o = 32; o > 0; o >>= 1) v += __shfl_down(v, o, 64);
    int lane = threadIdx.x & 63, wv = threadIdx.x >> 6;
    if (lane == 0) red[wv] = v;
    __syncthreads();
    return red[0] + red[1] + red[2] + red[3];
}

__device__ __forceinline__ float blockReduceMax(float v) {
    __shared__ float redm[4];
    __syncthreads();
#pragma unroll
    for (int o = 32; o > 0; o >>= 1) v = fmaxf(v, __shfl_down(v, o, 64));
    int lane = threadIdx.x & 63, wv = threadIdx.x >> 6;
    if (lane == 0) redm[wv] = v;
    __syncthreads();
    return fmaxf(fmaxf(redm[0], redm[1]), fmaxf(redm[2], redm[3]));
}

// ============ weight prep: w[k][cout][cin][tap] f32 -> bf16 frag-major ============
// dst: [k][cb][tap] blocks of 4096 ush, inner [n][g][l16][e]  (n=cout/16, l16=cout%16,
// g=c32/8, e=c32%8) — so the 8 KB tap-slab is LINEAR in the LDS frag layout.
__global__ __launch_bounds__(128) void wprep_k(const float* __restrict__ w,
                                               ushort* __restrict__ wt) {
    __shared__ float ld[1152];
    const int k = blockIdx.x >> 7, cout = blockIdx.x & 127;
    const float* src = w + (size_t)(k * 128 + cout) * 1152;
    for (int i = threadIdx.x; i < 1152; i += 128) ld[i] = src[i];
    __syncthreads();
    const int n = cout >> 4, l16 = cout & 15;
    for (int e = threadIdx.x; e < 1152; e += 128) {
        int cb = e / 288, r = e - cb * 288, tap = r >> 5, c32 = r & 31;
        int cin = cb * 32 + c32;
        size_t d = (size_t)((k * 4 + cb) * 9 + tap) * 4096
                 + n * 512 + (c32 >> 3) * 128 + l16 * 8 + (c32 & 7);
        wt[d] = f2b(ld[cin * 9 + tap]);
    }
}

// ============ conv1: block per (b,k); x in LDS, weights in VGPRs ============
// thread = 8 couts (l&15) x pixel-stride-16 (l>>4); 16B coalesced stores.
__global__ __launch_bounds__(TPB) void conv1_k(const float* __restrict__ x,
                                               const float* __restrict__ w1,
                                               const float* __restrict__ b1,
                                               ushort* __restrict__ h1, int bk0) {
    __shared__ float xs[1600];
    const int bkL = blockIdx.x;
    const int bk = bk0 + bkL;
    const int b = bk / Kc, k = bk - b * Kc;
    for (int i = threadIdx.x; i < 400; i += TPB)
        ((f32x4*)xs)[i] = ((const f32x4*)(x + b * 1600))[i];
    const int c8 = (threadIdx.x & 15) * 8;
    const int pg = threadIdx.x >> 4;         // 0..15
    float wr[72];
    const float* wp = w1 + (size_t)(k * 128 + c8) * 9;
#pragma unroll
    for (int j = 0; j < 18; ++j) ((f32x4*)wr)[j] = ((const f32x4*)wp)[j];
    float bias8[8];
#pragma unroll
    for (int j = 0; j < 8; ++j) bias8[j] = b1[k * 128 + c8 + j];
    __syncthreads();
    ushort* hb = h1 + (size_t)bkL * 361 * 128 + c8;
    for (int p = pg; p < 361; p += 16) {
        int py = p / 19, px = p - py * 19;
        const float* xb = xs + py * 80 + px * 2;
        float xt[9];
#pragma unroll
        for (int dy = 0; dy < 3; ++dy)
#pragma unroll
            for (int dx = 0; dx < 3; ++dx) xt[dy * 3 + dx] = xb[dy * 40 + dx];
        s16x8 v;
#pragma unroll
        for (int j = 0; j < 8; ++j) {
            float s = bias8[j];
#pragma unroll
            for (int t9 = 0; t9 < 9; ++t9) s += wr[j * 9 + t9] * xt[t9];
            v[j] = (short)f2b(fmaxf(s, 0.f));
        }
        *(s16x8*)(hb + (size_t)p * 128) = v;
    }
}

// ============ MFMA implicit-GEMM conv ============
// Block = (k, IBK b's). 4 waves = 2 m-groups x 2 n-groups; wave = MW m-frags x 4 n-frags
// (register B/A reuse). A input-patch in LDS (stride-40 rows, XOR chunk swizzle).
// B (weights) double-buffered in LDS via global_load_lds w16, prefetched 1 tap ahead.
// Grid k-clustered per XCD: i -> xcd=i&7, k=xcd*3+(i>>3)%3 (L2 sees 3 weight slabs).
template <int IH, int IW, int OH, int OW, int ST, int IBK, int MW>
__global__ __launch_bounds__(256) void mfconv_k(
    const ushort* __restrict__ hin, const ushort* __restrict__ wt,
    const float* __restrict__ bias, ushort* __restrict__ hout) {
    constexpr int IP = IH * IW, OP = OH * OW, MR = IBK * OP;
    __shared__ ushort As[IBK * IP * 40];
    __shared__ ushort Bs[2 * 4096];
    const int bi = blockIdx.x;
    const int xcd = bi & 7, j = bi >> 3;
    const int k = xcd * 3 + j % 3, grp = j / 3;
    const int bkL0 = (grp * IBK) * 24 + k;
    const int tid = threadIdx.x;
    const int w = tid >> 6, l = tid & 63, l16 = l & 15, g = l >> 4;
    const int mgrp = w >> 1, ngrp = w & 1;
    const ushort* wk = wt + (size_t)k * 36 * 4096;

    f32x4 acc[MW][4];
#pragma unroll
    for (int m = 0; m < MW; ++m)
#pragma unroll
        for (int n = 0; n < 4; ++n) acc[m][n] = (f32x4)0.f;

    int ibase[MW];
#pragma unroll
    for (int m = 0; m < MW; ++m) {
        int row = (mgrp * MW + m) * 16 + l16;
        row = row < MR ? row : MR - 1;
        int b = row / OP, pix = row - b * OP;
        int oy = pix / OW, ox = pix - oy * OW;
        ibase[m] = b * IP + oy * ST * IW + ox * ST;
    }

    // initial B prefetch (cb=0, tap=0) into buf 0
    {
        const int sl = w * 2;
        gload_lds16(wk + sl * 512 + l * 8, Bs + sl * 512);
        gload_lds16(wk + (sl + 1) * 512 + l * 8, Bs + (sl + 1) * 512);
    }

    for (int cb = 0; cb < 4; ++cb) {
        // stage A slab (32 cins) for all IBK patches
        for (int t = tid; t < IBK * IP * 4; t += 256) {
            int row = t >> 2, gc = t & 3;
            int b = row / IP, ipx = row - b * IP;
            s16x8 v = *(const s16x8*)(hin + ((size_t)(bkL0 + b * 24) * IP + ipx) * 128 + cb * 32 + gc * 8);
            *(s16x8*)(As + row * 40 + 8 * (gc ^ ((row >> 3) & 1))) = v;
        }
        __syncthreads();
#pragma unroll
        for (int tap = 0; tap < 9; ++tap) {
            const int it = cb * 9 + tap;
            const ushort* Bc = Bs + (it & 1) * 4096;
            if (it < 35) {      // prefetch next tap's 8 KB into other buffer
                ushort* Bnx = Bs + ((it & 1) ^ 1) * 4096;
                const ushort* src = wk + (size_t)(it + 1) * 4096;
                const int sl = w * 2;
                gload_lds16(src + sl * 512 + l * 8, Bnx + sl * 512);
                gload_lds16(src + (sl + 1) * 512 + l * 8, Bnx + (sl + 1) * 512);
            }
            const int ioff = (tap / 3) * IW + (tap % 3);
            s16x8 a[MW];
#pragma unroll
            for (int m = 0; m < MW; ++m) {
                int ip = ibase[m] + ioff;
                a[m] = *(const s16x8*)(As + ip * 40 + 8 * (g ^ ((ip >> 3) & 1)));
            }
#pragma unroll
            for (int n = 0; n < 4; ++n) {
                s16x8 bb = *(const s16x8*)(Bc + (ngrp * 4 + n) * 512 + g * 128 + l16 * 8);
#pragma unroll
                for (int m = 0; m < MW; ++m)
                    acc[m][n] = __builtin_amdgcn_mfma_f32_16x16x32_bf16(a[m], bb, acc[m][n], 0, 0, 0);
            }
            __syncthreads();
        }
    }
    // epilogue: C/D map col=lane&15, row=(lane>>4)*4+r
#pragma unroll
    for (int n = 0; n < 4; ++n) {
        int cout = (ngrp * 4 + n) * 16 + l16;
        float bv = bias[k * 128 + cout];
#pragma unroll
        for (int m = 0; m < MW; ++m) {
#pragma unroll
            for (int r = 0; r < 4; ++r) {
                int row = (mgrp * MW + m) * 16 + g * 4 + r;
                if (row < MR) {
                    int b = row / OP, opix = row - b * OP;
                    float v2 = fmaxf(acc[m][n][r] + bv, 0.f);
                    hout[((size_t)(bkL0 + b * 24) * OP + opix) * 128 + cout] = f2b(v2);
                }
            }
        }
    }
}

// ============ conv5 (1x1) + attention + pooling + heads + ocae assembly ============
__global__ __launch_bounds__(TPB) void head_k(const ushort* __restrict__ h4,
                                              const float* __restrict__ w5,
                                              const float* __restrict__ b5,
                                              const float* __restrict__ tpl,
                                              float* __restrict__ pose,
                                              float* __restrict__ dmv,
                                              float* __restrict__ out, int bk0) {
    __shared__ float h4s[128 * 25];   // [c][pix]
    __shared__ float outs[16 * 25];   // [f][pix]
    __shared__ float atts[25];
    __shared__ float pooled[16];
    const int bk = bk0 + blockIdx.x;
    const int k = bk % Kc;
    const ushort* hb = h4 + (size_t)blockIdx.x * 25 * 128;
    for (int i = threadIdx.x; i < 25 * 128; i += TPB) {
        int pix = i >> 7, c = i & 127;
        h4s[c * 25 + pix] = b2f(hb[i]);
    }
    __syncthreads();
    for (int t = threadIdx.x; t < 400; t += TPB) {
        int f = t / 25, pix = t - f * 25;
        const float* wp = w5 + (size_t)(k * 16 + f) * 128;
        float s = b5[k * 16 + f];
        for (int c = 0; c < 128; ++c) s += wp[c] * h4s[c * 25 + pix];
        outs[t] = s;
    }
    __syncthreads();
    if (threadIdx.x < 25) {
        int y5 = threadIdx.x / 5;
        const float* row = outs + 15 * 25 + y5 * 5;
        float mx = row[0];
#pragma unroll
        for (int j = 1; j < 5; ++j) mx = fmaxf(mx, row[j]);
        float ssum = 0.f;
#pragma unroll
        for (int j = 0; j < 5; ++j) ssum += expf(row[j] - mx);
        atts[threadIdx.x] = expf(outs[15 * 25 + threadIdx.x] - mx) / ssum;
    }
    __syncthreads();
    if (threadIdx.x < 15) {
        float s = 0.f;
        const float* row = outs + threadIdx.x * 25;
#pragma unroll
        for (int p = 0; p < 25; ++p) s += row[p] * atts[p];
        pooled[threadIdx.x] = s;
    }
    __syncthreads();
    float* oc = out + OUT_OC + (size_t)bk * 136;
    if (threadIdx.x < 6) {
        float v = fmaxf(pooled[threadIdx.x], 0.f);
        pose[bk * 6 + threadIdx.x] = v;
        oc[1 + threadIdx.x] = v;
        out[OUT_XM + bk * 6 + threadIdx.x] = v;
    } else if (threadIdx.x == 6) {
        float d = 1.f / (1.f + expf(-pooled[6]));
        dmv[bk] = d;
        oc[0] = d;
        out[OUT_DM + bk] = d;
    } else if (threadIdx.x >= 7 && threadIdx.x < 15) {
        oc[128 + threadIdx.x - 7] = fmaxf(pooled[threadIdx.x], 0.f);
    }
    for (int t = threadIdx.x; t < 121; t += TPB) oc[7 + t] = tpl[k * 121 + t];
}

// ============ affine warp + bilinear TS->40x40, fused mix-softmax stats ============
__device__ __forceinline__ float tapf(const float* tp, int y, int x) {
    bool valid = (x >= 0) && (x < TSz) && (y >= 0) && (y < TSz);
    int yc = min(max(y, 0), TSz - 1), xc = min(max(x, 0), TSz - 1);
    float v = tp[yc * TSz + xc];
    return valid ? v : 0.f;
}

__global__ __launch_bounds__(TPB) void warp_mix_k(const float* __restrict__ pose,
                                                  const float* __restrict__ tpl,
                                                  const float* __restrict__ dmv,
                                                  float* __restrict__ tt,
                                                  float* __restrict__ mxs) {
    __shared__ float tp[121];
    const int bk = blockIdx.x, k = bk % Kc;
    for (int i = threadIdx.x; i < 121; i += TPB) tp[i] = tpl[k * 121 + i];
    const float* ps = pose + bk * 6;
    const float D2R = 0.017453292519943295f;
    float ang = ps[0] * D2R, tx = ps[1], ty = ps[2];
    float sc = fmaxf(ps[3], 1e-2f);
    float shx = ps[4] * D2R, shy = ps[5] * D2R;
    float cams = cosf(ang - shy), sams = sinf(ang - shy);
    float cshy = cosf(shy), tshx = tanf(shx);
    float av = cams / cshy;
    float bv = -cams * tshx / cshy - sinf(ang);
    float cv = sams / cshy;
    float dv = -sams * tshx / cshy + cosf(ang);
    float m0 = dv / sc, m1 = -bv / sc, m3 = -cv / sc, m4 = av / sc;
    float m2 = m0 * (-5.f - tx) + m1 * (-5.f - ty) + 5.f;
    float m5 = m3 * (-5.f - tx) + m4 * (-5.f - ty) + 5.f;
    __syncthreads();
    float* to = tt + (size_t)bk * 1600;
    float tvl[7];
#pragma unroll
    for (int r = 0; r < 7; ++r) {
        int p = threadIdx.x + r * TPB;
        float val = 0.f;
        if (p < 1600) {
            int i = p / 40, jx = p - (p / 40) * 40;
            float gx = (jx + 0.5f) * (11.f / 40.f) - 0.5f;
            float gy = (i + 0.5f) * (11.f / 40.f) - 0.5f;
            float xin = m0 * gx + m1 * gy + m2;
            float yin = m3 * gx + m4 * gy + m5;
            float x0 = floorf(xin), y0 = floorf(yin);
            float wx = xin - x0, wy = yin - y0;
            int x0i = (int)x0, y0i = (int)y0;
            float v00 = tapf(tp, y0i, x0i),     v01 = tapf(tp, y0i, x0i + 1);
            float v10 = tapf(tp, y0i + 1, x0i), v11 = tapf(tp, y0i + 1, x0i + 1);
            val = v00 * (1.f - wx) * (1.f - wy) + v01 * wx * (1.f - wy) +
                  v10 * (1.f - wx) * wy + v11 * wx * wy;
            to[p] = val;
        }
        tvl[r] = val;
    }
    const float dm = dmv[bk];
    float mx = -1e30f;
#pragma unroll
    for (int r = 0; r < 7; ++r) {
        int p = threadIdx.x + r * TPB;
        if (p < 1600) mx = fmaxf(mx, dm * tvl[r]);
    }
    mx = blockReduceMax(mx);
    float s = 0.f;
#pragma unroll
    for (int r = 0; r < 7; ++r) {
        int p = threadIdx.x + r * TPB;
        if (p < 1600) s += expf(dm * tvl[r] - mx);
    }
    s = blockReduceSum(s);
    if (threadIdx.x == 0) { mxs[bk * 2] = mx; mxs[bk * 2 + 1] = s; }
}

// ============ per-sample std stats ============
__global__ __launch_bounds__(TPB) void std_k(const float* __restrict__ x,
                                             float* __restrict__ st) {
    const int b = blockIdx.x;
    const float* xb = x + b * 1600;
    float s = 0.f, s2 = 0.f;
    for (int p = threadIdx.x; p < 1600; p += TPB) {
        float v = xb[p];
        s += v; s2 += v * v;
    }
    s = blockReduceSum(s);
    s2 = blockReduceSum(s2);
    if (threadIdx.x == 0) {
        float mean = s / 1600.f;
        float var = (s2 - 1600.f * mean * mean) / 1599.f;
        float sd = sqrtf(var);
        st[b * 2] = rsqrtf(sd * 6.283185307179586f);   // mult
        st[b * 2 + 1] = -1.f / (2.f * sd * sd);        // pw
    }
}

// ============ log-likelihood, split over 8 pixel-blocks per sample ============
__global__ __launch_bounds__(TPB) void ll_k(const float* __restrict__ x,
                                            const float* __restrict__ tt,
                                            const float* __restrict__ dmv,
                                            const float* __restrict__ mxs,
                                            const float* __restrict__ st,
                                            float* __restrict__ part) {
    const int b = blockIdx.x, sp = blockIdx.y;
    __shared__ float dms[24], mxh[24], sih[24];
    if (threadIdx.x < 24) {
        int bk = b * 24 + threadIdx.x;
        dms[threadIdx.x] = dmv[bk];
        mxh[threadIdx.x] = mxs[bk * 2];
        sih[threadIdx.x] = 1.f / mxs[bk * 2 + 1];
    }
    __syncthreads();
    const float mult = st[b * 2], pw = st[b * 2 + 1];
    const float* xb = x + b * 1600;
    const float* tb = tt + (size_t)b * 24 * 1600;
    float acc = 0.f;
    int p = sp * 200 + threadIdx.x;
    if (threadIdx.x < 200) {
        float xv = xb[p];
        float ssum = 0.f;
        for (int k = 0; k < 24; ++k) {
            float tv = tb[(size_t)k * 1600 + p];
            float dd = xv - tv;
            float g = mult * expf(dd * dd * pw);
            float mixv = expf(dms[k] * tv - mxh[k]) * sih[k];
            ssum += g * mixv;
        }
        acc = logf(ssum);
    }
    acc = blockReduceSum(acc);
    if (threadIdx.x == 0) part[b * 8 + sp] = acc;
}

__global__ void fin_k(const float* __restrict__ part, float* __restrict__ out) {
    float v = 0.f;
#pragma unroll
    for (int q = 0; q < 8; ++q) v += part[threadIdx.x * 8 + q];
#pragma unroll
    for (int o = 32; o > 0; o >>= 1) v += __shfl_down(v, o, 64);
    if (threadIdx.x == 0) out[0] = v * (1.f / 64.f);
}

// ============ launch ============
extern "C" void kernel_launch(void* const* d_in, const int* in_sizes, int n_in,
                              void* d_out, int out_size, void* d_ws, size_t ws_size,
                              hipStream_t stream) {
    const float* x   = (const float*)d_in[0];
    const float* w1  = (const float*)d_in[1];
    const float* b1  = (const float*)d_in[2];
    const float* w2  = (const float*)d_in[3];
    const float* b2  = (const float*)d_in[4];
    const float* w3  = (const float*)d_in[5];
    const float* b3  = (const float*)d_in[6];
    const float* w4  = (const float*)d_in[7];
    const float* b4  = (const float*)d_in[8];
    const float* w5  = (const float*)d_in[9];
    const float* b5  = (const float*)d_in[10];
    const float* tpl = (const float*)d_in[11];
    float* out = (float*)d_out;
    char* W = (char*)d_ws;

    ushort* wt2 = (ushort*)(W + OFFB_W2);
    ushort* wt3 = (ushort*)(W + OFFB_W3);
    ushort* wt4 = (ushort*)(W + OFFB_W4);
    ushort* h1u = (ushort*)(W + OFFB_H1);
    ushort* h2u = (ushort*)(W + OFFB_H2);
    ushort* h3u = (ushort*)(W + OFFB_H3);
    ushort* h4u = (ushort*)(W + OFFB_H4);
    float*  pose = (float*)(W + OFFB_POSE);
    float*  dmv  = (float*)(W + OFFB_DMV);
    float*  ttb  = (float*)(W + OFFB_TT);
    float*  stv  = (float*)(W + OFFB_ST);
    float*  mxs  = (float*)(W + OFFB_MXS);
    float*  part = (float*)(W + OFFB_PART);

    wprep_k<<<Kc * 128, 128, 0, stream>>>(w2, wt2);
    wprep_k<<<Kc * 128, 128, 0, stream>>>(w3, wt3);
    wprep_k<<<Kc * 128, 128, 0, stream>>>(w4, wt4);
    std_k<<<Bn, TPB, 0, stream>>>(x, stv);

    for (int ch = 0; ch < NCHUNK; ++ch) {
        int bk0 = ch * CH;
        conv1_k<<<CH, TPB, 0, stream>>>(x, w1, b1, h1u, bk0);
        mfconv_k<19, 19, 9, 9, 2, 1, 3><<<768, 256, 0, stream>>>(h1u, wt2, b2, h2u);
        mfconv_k<9, 9, 7, 7, 1, 2, 4><<<384, 256, 0, stream>>>(h2u, wt3, b3, h3u);
        mfconv_k<7, 7, 5, 5, 1, 2, 2><<<384, 256, 0, stream>>>(h3u, wt4, b4, h4u);
        head_k<<<CH, TPB, 0, stream>>>(h4u, w5, b5, tpl, pose, dmv, out, bk0);
    }

    warp_mix_k<<<NBK, TPB, 0, stream>>>(pose, tpl, dmv, ttb, mxs);
    ll_k<<<dim3(Bn, 8), TPB, 0, stream>>>(x, ttb, dmv, mxs, stv, part);
    fin_k<<<1, 64, 0, stream>>>(part, out);
}

// Round 6
// 313.406 us; speedup vs baseline: 9.7249x; 1.0050x over previous
//
#include <hip/hip_runtime.h>
#include <math.h>

#define TPB 256

typedef __attribute__((ext_vector_type(8))) short s16x8;
typedef __attribute__((ext_vector_type(4))) float f32x4;
typedef unsigned int u32;

constexpr int Bn = 64, Kc = 24, TSz = 11;
constexpr int NBK = Bn * Kc;          // 1536
constexpr int CH = 768;               // (b,k) instances per chunk
constexpr int NCHUNK = NBK / CH;      // 2
constexpr int P1 = 361, P2 = 81, P3 = 49, P4 = 25;

// ---- workspace offsets (BYTES) ----
constexpr size_t SZW_B    = (size_t)Kc * 36 * 4096 * 2;      // 7,077,888 B/plane
constexpr size_t OFFB_W2  = 0;
constexpr size_t OFFB_W3  = OFFB_W2 + SZW_B;
constexpr size_t OFFB_W4  = OFFB_W3 + SZW_B;
constexpr size_t OFFB_H1  = OFFB_W4 + SZW_B;
constexpr size_t OFFB_H2  = OFFB_H1 + (size_t)CH * P1 * 128 * 2;
constexpr size_t OFFB_H3  = OFFB_H2 + (size_t)CH * P2 * 128 * 2;
constexpr size_t OFFB_H4  = OFFB_H3 + (size_t)CH * P3 * 128 * 2;
constexpr size_t OFFB_POSE= OFFB_H4 + (size_t)CH * P4 * 128 * 2;
constexpr size_t OFFB_DMV = OFFB_POSE + (size_t)NBK * 6 * 4;
constexpr size_t OFFB_TT  = OFFB_DMV + (size_t)NBK * 4;
constexpr size_t OFFB_ST  = OFFB_TT + (size_t)NBK * 1600 * 4;
constexpr size_t OFFB_MXS = OFFB_ST + 512;
constexpr size_t OFFB_PART= OFFB_MXS + (size_t)NBK * 2 * 4;

// ---- output offsets (floats) ----
constexpr int OUT_OC = 1;                   // input_ocae [B,K,136]
constexpr int OUT_XM = 1 + NBK * 136;
constexpr int OUT_DM = OUT_XM + NBK * 6;

// ============ bf16 helpers ============
__device__ __forceinline__ ushort f2b(float f) {
    union { float f; unsigned u; } c; c.f = f;
    unsigned r = c.u + 0x7fffu + ((c.u >> 16) & 1u);
    return (ushort)(r >> 16);
}
__device__ __forceinline__ float b2f(ushort h) {
    union { unsigned u; float f; } c; c.u = ((unsigned)h) << 16; return c.f;
}

// ============ reductions (TPB=256 → 4 waves) ============
__device__ __forceinline__ float blockReduceSum(float v) {
    __shared__ float red[4];
    __syncthreads();
#pragma unroll
    for (int o = 32; o > 0; o >>= 1) v += __shfl_down(v, o, 64);
    int lane = threadIdx.x & 63, wv = threadIdx.x >> 6;
    if (lane == 0) red[wv] = v;
    __syncthreads();
    return red[0] + red[1] + red[2] + red[3];
}

__device__ __forceinline__ float blockReduceMax(float v) {
    __shared__ float redm[4];
    __syncthreads();
#pragma unroll
    for (int o = 32; o > 0; o >>= 1) v = fmaxf(v, __shfl_down(v, o, 64));
    int lane = threadIdx.x & 63, wv = threadIdx.x >> 6;
    if (lane == 0) redm[wv] = v;
    __syncthreads();
    return fmaxf(fmaxf(redm[0], redm[1]), fmaxf(redm[2], redm[3]));
}

// ============ weight prep: w[k][cout][cin][tap] f32 -> bf16 frag-major ============
// dst: [k][cb][tap] blocks of 4096 ush, inner [n][g][l16][e]  (n=cout/16, l16=cout%16,
// g=c32/8, e=c32%8) — 1 KB contiguous per (n) fragment = perfectly coalesced wave load.
__global__ __launch_bounds__(128) void wprep_k(const float* __restrict__ w,
                                               ushort* __restrict__ wt) {
    __shared__ float ld[1152];
    const int k = blockIdx.x >> 7, cout = blockIdx.x & 127;
    const float* src = w + (size_t)(k * 128 + cout) * 1152;
    for (int i = threadIdx.x; i < 1152; i += 128) ld[i] = src[i];
    __syncthreads();
    const int n = cout >> 4, l16 = cout & 15;
    for (int e = threadIdx.x; e < 1152; e += 128) {
        int cb = e / 288, r = e - cb * 288, tap = r >> 5, c32 = r & 31;
        int cin = cb * 32 + c32;
        size_t d = (size_t)((k * 4 + cb) * 9 + tap) * 4096
                 + n * 512 + (c32 >> 3) * 128 + l16 * 8 + (c32 & 7);
        wt[d] = f2b(ld[cin * 9 + tap]);
    }
}

// ============ conv1: block per (b,k); x in LDS, weights in VGPRs ============
__global__ __launch_bounds__(TPB) void conv1_k(const float* __restrict__ x,
                                               const float* __restrict__ w1,
                                               const float* __restrict__ b1,
                                               ushort* __restrict__ h1, int bk0) {
    __shared__ float xs[1600];
    const int bkL = blockIdx.x;
    const int bk = bk0 + bkL;
    const int b = bk / Kc, k = bk - b * Kc;
    for (int i = threadIdx.x; i < 400; i += TPB)
        ((f32x4*)xs)[i] = ((const f32x4*)(x + b * 1600))[i];
    const int c8 = (threadIdx.x & 15) * 8;
    const int pg = threadIdx.x >> 4;         // 0..15
    float wr[72];
    const float* wp = w1 + (size_t)(k * 128 + c8) * 9;
#pragma unroll
    for (int j = 0; j < 18; ++j) ((f32x4*)wr)[j] = ((const f32x4*)wp)[j];
    float bias8[8];
#pragma unroll
    for (int j = 0; j < 8; ++j) bias8[j] = b1[k * 128 + c8 + j];
    __syncthreads();
    ushort* hb = h1 + (size_t)bkL * 361 * 128 + c8;
    for (int p = pg; p < 361; p += 16) {
        int py = p / 19, px = p - py * 19;
        const float* xb = xs + py * 80 + px * 2;
        float xt[9];
#pragma unroll
        for (int dy = 0; dy < 3; ++dy)
#pragma unroll
            for (int dx = 0; dx < 3; ++dx) xt[dy * 3 + dx] = xb[dy * 40 + dx];
        s16x8 v;
#pragma unroll
        for (int j = 0; j < 8; ++j) {
            float s = bias8[j];
#pragma unroll
            for (int t9 = 0; t9 < 9; ++t9) s += wr[j * 9 + t9] * xt[t9];
            v[j] = (short)f2b(fmaxf(s, 0.f));
        }
        *(s16x8*)(hb + (size_t)p * 128) = v;
    }
}

// ============ MFMA implicit-GEMM conv ============
// Block = (k, IBK b's). 4 waves = 2 m-groups x 2 n-groups; wave = MW m-frags x 4 n-frags.
// A input-patch in LDS (stride-40 rows, XOR chunk swizzle); barriers ONLY around A stage.
// B (weights) in per-wave REGISTER double-buffer, prefetched 1 tap ahead via plain
// global loads — register loads stay in flight across barriers (no vmcnt drain).
// cb loop fully unrolled so the buffer parity (it&1) is compile-time (no scratch).
template <int IH, int IW, int OH, int OW, int ST, int IBK, int MW>
__global__ __launch_bounds__(256) void mfconv_k(
    const ushort* __restrict__ hin, const ushort* __restrict__ wt,
    const float* __restrict__ bias, ushort* __restrict__ hout) {
    constexpr int IP = IH * IW, OP = OH * OW, MR = IBK * OP;
    __shared__ ushort As[IBK * IP * 40];
    const int bi = blockIdx.x;
    const int xcd = bi & 7, j = bi >> 3;
    const int k = xcd * 3 + j % 3, grp = j / 3;
    const int bkL0 = (grp * IBK) * 24 + k;
    const int tid = threadIdx.x;
    const int w = tid >> 6, l = tid & 63, l16 = l & 15, g = l >> 4;
    const int mgrp = w >> 1, ngrp = w & 1;
    // per-lane B base: frag n at +n*512, tap-slab it at +it*4096 (ushort units)
    const ushort* wb = wt + (size_t)k * 36 * 4096 + ngrp * 2048 + g * 128 + l16 * 8;

    f32x4 acc[MW][4];
#pragma unroll
    for (int m = 0; m < MW; ++m)
#pragma unroll
        for (int n = 0; n < 4; ++n) acc[m][n] = (f32x4)0.f;

    int ibase[MW];
#pragma unroll
    for (int m = 0; m < MW; ++m) {
        int row = (mgrp * MW + m) * 16 + l16;
        row = row < MR ? row : MR - 1;
        int b = row / OP, pix = row - b * OP;
        int oy = pix / OW, ox = pix - oy * OW;
        ibase[m] = b * IP + oy * ST * IW + ox * ST;
    }

    s16x8 breg[2][4];
#pragma unroll
    for (int n = 0; n < 4; ++n) breg[0][n] = *(const s16x8*)(wb + n * 512);

#pragma unroll
    for (int cb = 0; cb < 4; ++cb) {
        if (cb) __syncthreads();            // prev taps' A reads done
        for (int t = tid; t < IBK * IP * 4; t += 256) {
            int row = t >> 2, gc = t & 3;
            int b = row / IP, ipx = row - b * IP;
            s16x8 v = *(const s16x8*)(hin + ((size_t)(bkL0 + b * 24) * IP + ipx) * 128 + cb * 32 + gc * 8);
            *(s16x8*)(As + row * 40 + 8 * (gc ^ ((row >> 3) & 1))) = v;
        }
        __syncthreads();
#pragma unroll
        for (int tap = 0; tap < 9; ++tap) {
            constexpr int dummy = 0; (void)dummy;
            const int it = cb * 9 + tap;          // compile-time (both loops unrolled)
            if (it < 35) {                        // prefetch tap+1 into other reg buffer
                const ushort* src = wb + (size_t)(it + 1) * 4096;
#pragma unroll
                for (int n = 0; n < 4; ++n)
                    breg[(it + 1) & 1][n] = *(const s16x8*)(src + n * 512);
            }
            const int ioff = (tap / 3) * IW + (tap % 3);
            s16x8 a[MW];
#pragma unroll
            for (int m = 0; m < MW; ++m) {
                int ip = ibase[m] + ioff;
                a[m] = *(const s16x8*)(As + ip * 40 + 8 * (g ^ ((ip >> 3) & 1)));
            }
#pragma unroll
            for (int n = 0; n < 4; ++n) {
#pragma unroll
                for (int m = 0; m < MW; ++m)
                    acc[m][n] = __builtin_amdgcn_mfma_f32_16x16x32_bf16(a[m], breg[it & 1][n], acc[m][n], 0, 0, 0);
            }
        }
    }
    // epilogue: C/D map col=lane&15, row=(lane>>4)*4+r
#pragma unroll
    for (int n = 0; n < 4; ++n) {
        int cout = (ngrp * 4 + n) * 16 + l16;
        float bv = bias[k * 128 + cout];
#pragma unroll
        for (int m = 0; m < MW; ++m) {
#pragma unroll
            for (int r = 0; r < 4; ++r) {
                int row = (mgrp * MW + m) * 16 + g * 4 + r;
                if (row < MR) {
                    int b = row / OP, opix = row - b * OP;
                    float v2 = fmaxf(acc[m][n][r] + bv, 0.f);
                    hout[((size_t)(bkL0 + b * 24) * OP + opix) * 128 + cout] = f2b(v2);
                }
            }
        }
    }
}

// ============ conv5 (1x1) + attention + pooling + heads + ocae assembly ============
__global__ __launch_bounds__(TPB) void head_k(const ushort* __restrict__ h4,
                                              const float* __restrict__ w5,
                                              const float* __restrict__ b5,
                                              const float* __restrict__ tpl,
                                              float* __restrict__ pose,
                                              float* __restrict__ dmv,
                                              float* __restrict__ out, int bk0) {
    __shared__ float h4s[128 * 25];   // [c][pix]
    __shared__ float outs[16 * 25];   // [f][pix]
    __shared__ float atts[25];
    __shared__ float pooled[16];
    const int bk = bk0 + blockIdx.x;
    const int k = bk % Kc;
    const ushort* hb = h4 + (size_t)blockIdx.x * 25 * 128;
    for (int i = threadIdx.x; i < 25 * 128; i += TPB) {
        int pix = i >> 7, c = i & 127;
        h4s[c * 25 + pix] = b2f(hb[i]);
    }
    __syncthreads();
    for (int t = threadIdx.x; t < 400; t += TPB) {
        int f = t / 25, pix = t - f * 25;
        const float* wp = w5 + (size_t)(k * 16 + f) * 128;
        float s = b5[k * 16 + f];
        for (int c = 0; c < 128; ++c) s += wp[c] * h4s[c * 25 + pix];
        outs[t] = s;
    }
    __syncthreads();
    if (threadIdx.x < 25) {
        int y5 = threadIdx.x / 5;
        const float* row = outs + 15 * 25 + y5 * 5;
        float mx = row[0];
#pragma unroll
        for (int j = 1; j < 5; ++j) mx = fmaxf(mx, row[j]);
        float ssum = 0.f;
#pragma unroll
        for (int j = 0; j < 5; ++j) ssum += expf(row[j] - mx);
        atts[threadIdx.x] = expf(outs[15 * 25 + threadIdx.x] - mx) / ssum;
    }
    __syncthreads();
    if (threadIdx.x < 15) {
        float s = 0.f;
        const float* row = outs + threadIdx.x * 25;
#pragma unroll
        for (int p = 0; p < 25; ++p) s += row[p] * atts[p];
        pooled[threadIdx.x] = s;
    }
    __syncthreads();
    float* oc = out + OUT_OC + (size_t)bk * 136;
    if (threadIdx.x < 6) {
        float v = fmaxf(pooled[threadIdx.x], 0.f);
        pose[bk * 6 + threadIdx.x] = v;
        oc[1 + threadIdx.x] = v;
        out[OUT_XM + bk * 6 + threadIdx.x] = v;
    } else if (threadIdx.x == 6) {
        float d = 1.f / (1.f + expf(-pooled[6]));
        dmv[bk] = d;
        oc[0] = d;
        out[OUT_DM + bk] = d;
    } else if (threadIdx.x >= 7 && threadIdx.x < 15) {
        oc[128 + threadIdx.x - 7] = fmaxf(pooled[threadIdx.x], 0.f);
    }
    for (int t = threadIdx.x; t < 121; t += TPB) oc[7 + t] = tpl[k * 121 + t];
}

// ============ affine warp + bilinear TS->40x40, fused mix-softmax stats ============
__device__ __forceinline__ float tapf(const float* tp, int y, int x) {
    bool valid = (x >= 0) && (x < TSz) && (y >= 0) && (y < TSz);
    int yc = min(max(y, 0), TSz - 1), xc = min(max(x, 0), TSz - 1);
    float v = tp[yc * TSz + xc];
    return valid ? v : 0.f;
}

__global__ __launch_bounds__(TPB) void warp_mix_k(const float* __restrict__ pose,
                                                  const float* __restrict__ tpl,
                                                  const float* __restrict__ dmv,
                                                  float* __restrict__ tt,
                                                  float* __restrict__ mxs) {
    __shared__ float tp[121];
    const int bk = blockIdx.x, k = bk % Kc;
    for (int i = threadIdx.x; i < 121; i += TPB) tp[i] = tpl[k * 121 + i];
    const float* ps = pose + bk * 6;
    const float D2R = 0.017453292519943295f;
    float ang = ps[0] * D2R, tx = ps[1], ty = ps[2];
    float sc = fmaxf(ps[3], 1e-2f);
    float shx = ps[4] * D2R, shy = ps[5] * D2R;
    float cams = cosf(ang - shy), sams = sinf(ang - shy);
    float cshy = cosf(shy), tshx = tanf(shx);
    float av = cams / cshy;
    float bv = -cams * tshx / cshy - sinf(ang);
    float cv = sams / cshy;
    float dv = -sams * tshx / cshy + cosf(ang);
    float m0 = dv / sc, m1 = -bv / sc, m3 = -cv / sc, m4 = av / sc;
    float m2 = m0 * (-5.f - tx) + m1 * (-5.f - ty) + 5.f;
    float m5 = m3 * (-5.f - tx) + m4 * (-5.f - ty) + 5.f;
    __syncthreads();
    float* to = tt + (size_t)bk * 1600;
    float tvl[7];
#pragma unroll
    for (int r = 0; r < 7; ++r) {
        int p = threadIdx.x + r * TPB;
        float val = 0.f;
        if (p < 1600) {
            int i = p / 40, jx = p - (p / 40) * 40;
            float gx = (jx + 0.5f) * (11.f / 40.f) - 0.5f;
            float gy = (i + 0.5f) * (11.f / 40.f) - 0.5f;
            float xin = m0 * gx + m1 * gy + m2;
            float yin = m3 * gx + m4 * gy + m5;
            float x0 = floorf(xin), y0 = floorf(yin);
            float wx = xin - x0, wy = yin - y0;
            int x0i = (int)x0, y0i = (int)y0;
            float v00 = tapf(tp, y0i, x0i),     v01 = tapf(tp, y0i, x0i + 1);
            float v10 = tapf(tp, y0i + 1, x0i), v11 = tapf(tp, y0i + 1, x0i + 1);
            val = v00 * (1.f - wx) * (1.f - wy) + v01 * wx * (1.f - wy) +
                  v10 * (1.f - wx) * wy + v11 * wx * wy;
            to[p] = val;
        }
        tvl[r] = val;
    }
    const float dm = dmv[bk];
    float mx = -1e30f;
#pragma unroll
    for (int r = 0; r < 7; ++r) {
        int p = threadIdx.x + r * TPB;
        if (p < 1600) mx = fmaxf(mx, dm * tvl[r]);
    }
    mx = blockReduceMax(mx);
    float s = 0.f;
#pragma unroll
    for (int r = 0; r < 7; ++r) {
        int p = threadIdx.x + r * TPB;
        if (p < 1600) s += expf(dm * tvl[r] - mx);
    }
    s = blockReduceSum(s);
    if (threadIdx.x == 0) { mxs[bk * 2] = mx; mxs[bk * 2 + 1] = s; }
}

// ============ per-sample std stats ============
__global__ __launch_bounds__(TPB) void std_k(const float* __restrict__ x,
                                             float* __restrict__ st) {
    const int b = blockIdx.x;
    const float* xb = x + b * 1600;
    float s = 0.f, s2 = 0.f;
    for (int p = threadIdx.x; p < 1600; p += TPB) {
        float v = xb[p];
        s += v; s2 += v * v;
    }
    s = blockReduceSum(s);
    s2 = blockReduceSum(s2);
    if (threadIdx.x == 0) {
        float mean = s / 1600.f;
        float var = (s2 - 1600.f * mean * mean) / 1599.f;
        float sd = sqrtf(var);
        st[b * 2] = rsqrtf(sd * 6.283185307179586f);   // mult
        st[b * 2 + 1] = -1.f / (2.f * sd * sd);        // pw
    }
}

// ============ log-likelihood, split over 8 pixel-blocks per sample ============
__global__ __launch_bounds__(TPB) void ll_k(const float* __restrict__ x,
                                            const float* __restrict__ tt,
                                            const float* __restrict__ dmv,
                                            const float* __restrict__ mxs,
                                            const float* __restrict__ st,
                                            float* __restrict__ part) {
    const int b = blockIdx.x, sp = blockIdx.y;
    __shared__ float dms[24], mxh[24], sih[24];
    if (threadIdx.x < 24) {
        int bk = b * 24 + threadIdx.x;
        dms[threadIdx.x] = dmv[bk];
        mxh[threadIdx.x] = mxs[bk * 2];
        sih[threadIdx.x] = 1.f / mxs[bk * 2 + 1];
    }
    __syncthreads();
    const float mult = st[b * 2], pw = st[b * 2 + 1];
    const float* xb = x + b * 1600;
    const float* tb = tt + (size_t)b * 24 * 1600;
    float acc = 0.f;
    int p = sp * 200 + threadIdx.x;
    if (threadIdx.x < 200) {
        float xv = xb[p];
        float ssum = 0.f;
        for (int k = 0; k < 24; ++k) {
            float tv = tb[(size_t)k * 1600 + p];
            float dd = xv - tv;
            float g = mult * expf(dd * dd * pw);
            float mixv = expf(dms[k] * tv - mxh[k]) * sih[k];
            ssum += g * mixv;
        }
        acc = logf(ssum);
    }
    acc = blockReduceSum(acc);
    if (threadIdx.x == 0) part[b * 8 + sp] = acc;
}

__global__ void fin_k(const float* __restrict__ part, float* __restrict__ out) {
    float v = 0.f;
#pragma unroll
    for (int q = 0; q < 8; ++q) v += part[threadIdx.x * 8 + q];
#pragma unroll
    for (int o = 32; o > 0; o >>= 1) v += __shfl_down(v, o, 64);
    if (threadIdx.x == 0) out[0] = v * (1.f / 64.f);
}

// ============ launch ============
extern "C" void kernel_launch(void* const* d_in, const int* in_sizes, int n_in,
                              void* d_out, int out_size, void* d_ws, size_t ws_size,
                              hipStream_t stream) {
    const float* x   = (const float*)d_in[0];
    const float* w1  = (const float*)d_in[1];
    const float* b1  = (const float*)d_in[2];
    const float* w2  = (const float*)d_in[3];
    const float* b2  = (const float*)d_in[4];
    const float* w3  = (const float*)d_in[5];
    const float* b3  = (const float*)d_in[6];
    const float* w4  = (const float*)d_in[7];
    const float* b4  = (const float*)d_in[8];
    const float* w5  = (const float*)d_in[9];
    const float* b5  = (const float*)d_in[10];
    const float* tpl = (const float*)d_in[11];
    float* out = (float*)d_out;
    char* W = (char*)d_ws;

    ushort* wt2 = (ushort*)(W + OFFB_W2);
    ushort* wt3 = (ushort*)(W + OFFB_W3);
    ushort* wt4 = (ushort*)(W + OFFB_W4);
    ushort* h1u = (ushort*)(W + OFFB_H1);
    ushort* h2u = (ushort*)(W + OFFB_H2);
    ushort* h3u = (ushort*)(W + OFFB_H3);
    ushort* h4u = (ushort*)(W + OFFB_H4);
    float*  pose = (float*)(W + OFFB_POSE);
    float*  dmv  = (float*)(W + OFFB_DMV);
    float*  ttb  = (float*)(W + OFFB_TT);
    float*  stv  = (float*)(W + OFFB_ST);
    float*  mxs  = (float*)(W + OFFB_MXS);
    float*  part = (float*)(W + OFFB_PART);

    wprep_k<<<Kc * 128, 128, 0, stream>>>(w2, wt2);
    wprep_k<<<Kc * 128, 128, 0, stream>>>(w3, wt3);
    wprep_k<<<Kc * 128, 128, 0, stream>>>(w4, wt4);
    std_k<<<Bn, TPB, 0, stream>>>(x, stv);

    for (int ch = 0; ch < NCHUNK; ++ch) {
        int bk0 = ch * CH;
        conv1_k<<<CH, TPB, 0, stream>>>(x, w1, b1, h1u, bk0);
        mfconv_k<19, 19, 9, 9, 2, 1, 3><<<768, 256, 0, stream>>>(h1u, wt2, b2, h2u);
        mfconv_k<9, 9, 7, 7, 1, 2, 4><<<384, 256, 0, stream>>>(h2u, wt3, b3, h3u);
        mfconv_k<7, 7, 5, 5, 1, 2, 2><<<384, 256, 0, stream>>>(h3u, wt4, b4, h4u);
        head_k<<<CH, TPB, 0, stream>>>(h4u, w5, b5, tpl, pose, dmv, out, bk0);
    }

    warp_mix_k<<<NBK, TPB, 0, stream>>>(pose, tpl, dmv, ttb, mxs);
    ll_k<<<dim3(Bn, 8), TPB, 0, stream>>>(x, ttb, dmv, mxs, stv, part);
    fin_k<<<1, 64, 0, stream>>>(part, out);
}